// Round 13
// baseline (1832.194 us; speedup 1.0000x reference)
//
#include <hip/hip_runtime.h>

#define N_NODES 100000
#define E_EDGES 1600000
#define EP (E_EDGES + N_NODES)
#define NG 1024
#define NEG 0.2f
#define EPS_BN 1e-5f
#define LOG2E 1.44269504088896f

#define NB 196        // dst buckets of 512 nodes
#define BCAP 12288    // per-bucket capacity (mean 8704)
#define NAGG (N_NODES / 4)   // k_agg grid
#define NSLOT 16      // BN partial slots

typedef __attribute__((ext_vector_type(8))) short bf8_t;
typedef __attribute__((ext_vector_type(4))) float f4_t;

__device__ __forceinline__ unsigned short f2b(float f) {   // f32 -> bf16 RNE
    unsigned u = __float_as_uint(f);
    u += 0x7FFF + ((u >> 16) & 1);
    return (unsigned short)(u >> 16);
}

// 16-lane sum via mov_dpp row_ror butterfly; result broadcast to 16 lanes.
__device__ __forceinline__ float rsum16(float p) {
    p += __int_as_float(__builtin_amdgcn_mov_dpp(__float_as_int(p), 0x128, 0xf, 0xf, true));
    p += __int_as_float(__builtin_amdgcn_mov_dpp(__float_as_int(p), 0x124, 0xf, 0xf, true));
    p += __int_as_float(__builtin_amdgcn_mov_dpp(__float_as_int(p), 0x122, 0xf, 0xf, true));
    p += __int_as_float(__builtin_amdgcn_mov_dpp(__float_as_int(p), 0x121, 0xf, 0xf, true));
    return p;
}

// 4-lane (quad) sum via quad_perm DPP; result broadcast to all 4 lanes.
__device__ __forceinline__ float quadsum(float p) {
    p += __int_as_float(__builtin_amdgcn_mov_dpp(__float_as_int(p), 0xB1, 0xf, 0xf, true)); // [1,0,3,2]
    p += __int_as_float(__builtin_amdgcn_mov_dpp(__float_as_int(p), 0x4E, 0xf, 0xf, true)); // [2,3,0,1]
    return p;
}

__device__ __forceinline__ void unpack8(const int4& d, float* z) {
    unsigned a = (unsigned)d.x, b = (unsigned)d.y, c = (unsigned)d.z, w = (unsigned)d.w;
    z[0] = __uint_as_float(a << 16); z[1] = __uint_as_float(a & 0xFFFF0000u);
    z[2] = __uint_as_float(b << 16); z[3] = __uint_as_float(b & 0xFFFF0000u);
    z[4] = __uint_as_float(c << 16); z[5] = __uint_as_float(c & 0xFFFF0000u);
    z[6] = __uint_as_float(w << 16); z[7] = __uint_as_float(w & 0xFFFF0000u);
}

// ================= CSR build: partition -> per-bucket build (packed int) =====
// buf entry = (src << 9) | (dst & 511); bucket = dst >> 9.
__global__ __launch_bounds__(256) void k_part(const int* __restrict__ ei,
                                              int* __restrict__ bucketCur,
                                              int* __restrict__ buf) {
    __shared__ int lh[NB], lb[NB];
    int t = threadIdx.x;
    for (int i = t; i < NB; i += 256) lh[i] = 0;
    __syncthreads();
    int base = blockIdx.x * 4096;
    int pk[16];
    int bk[16];
    int rk[16];
#pragma unroll
    for (int i = 0; i < 16; i++) {
        int idx = base + i * 256 + t;
        int s, d;
        if (idx < E_EDGES) { s = ei[idx]; d = ei[E_EDGES + idx]; }
        else if (idx < EP) { s = d = idx - E_EDGES; }
        else { s = 0; d = -1; }
        pk[i] = (s << 9) | (d & 511);
        bk[i] = d >> 9;
        rk[i] = (d >= 0) ? atomicAdd(&lh[d >> 9], 1) : 0;
    }
    __syncthreads();
    for (int i = t; i < NB; i += 256) lb[i] = atomicAdd(&bucketCur[i], lh[i]);
    __syncthreads();
#pragma unroll
    for (int i = 0; i < 16; i++) {
        int bkt = bk[i];
        if (bkt >= 0)
            buf[(size_t)bkt * BCAP + lb[bkt] + rk[i]] = pk[i];
    }
}

// per-bucket: histogram -> LDS scan -> startA/cntA -> place colA (byte offsets)
// + zero a 16-int tail pad after each bucket's used region (pipeline over-reads)
__global__ __launch_bounds__(512) void k_build(const int* __restrict__ buf,
                                               const int* __restrict__ bcnt,
                                               int* __restrict__ startA,
                                               int* __restrict__ cntA,
                                               int* __restrict__ colA) {
    __shared__ int h[512];
    __shared__ int s[512];
    int b = blockIdx.x, t = threadIdx.x;
    h[t] = 0;
    __syncthreads();
    int n = bcnt[b];
    const int* p = buf + (size_t)b * BCAP;
    for (int i = t; i < n; i += 512) atomicAdd(&h[p[i] & 511], 1);
    __syncthreads();
    int v = h[t];
    s[t] = v;
    __syncthreads();
    for (int o = 1; o < 512; o <<= 1) {
        int u = (t >= o) ? s[t - o] : 0;
        __syncthreads();
        s[t] += u;
        __syncthreads();
    }
    int myStart = b * BCAP + s[t] - v;   // exclusive prefix within bucket
    int node = (b << 9) + t;
    if (node < N_NODES) {
        startA[node] = myStart;
        cntA[node] = v;
    }
    h[t] = myStart;                      // reuse as running cursor
    __syncthreads();
    for (int i = t; i < n; i += 512) {
        int e = p[i];
        int r = atomicAdd(&h[e & 511], 1);
        colA[r] = (e >> 9) << 8;         // src * 256 (byte offset into xl)
    }
    if (t < 16) colA[b * BCAP + n + t] = 0;   // tail pad (stray reads -> node 0)
}

// === prep: wconv L1+L2 (blocks 0..31) + gstart (32..422) + zero (423..424) ===
__global__ __launch_bounds__(256) void k_prep(
    const float* __restrict__ Wl1, const float* __restrict__ Wr1,
    const float* __restrict__ Wl2, const float* __restrict__ Wr2,
    unsigned short* __restrict__ img1, unsigned short* __restrict__ img2,
    const int* __restrict__ batch, int* __restrict__ gstart,
    int* __restrict__ bucketCur, float* __restrict__ SP, int* __restrict__ done) {
    int blk = blockIdx.x;
    int t = threadIdx.x;
    if (blk < 32) {
        int lay = blk >> 4;
        int g = (blk & 15) * 256 + t;   // 4096 chunks per layer
        int m = g >> 11, n = (g >> 4) & 127, kb = g & 15;
        const float* W = lay ? (m ? Wr2 : Wl2) : (m ? Wr1 : Wl1);
        unsigned short* img = lay ? img2 : img1;
        unsigned short v[8];
#pragma unroll
        for (int j = 0; j < 8; j++) v[j] = f2b(W[(kb * 8 + j) * 128 + n]);
        int off = m * 32768 + n * 256 + kb * 16;
        *(int4*)((char*)img + off) = *(int4*)v;
    } else if (blk < 423) {
        int i = (blk - 32) * 256 + t;
        if (i >= N_NODES) return;
        int b = batch[i];
        int prev = (i == 0) ? -1 : batch[i - 1];
        for (int g = prev + 1; g <= b; g++) gstart[g] = i;
        if (i == N_NODES - 1)
            for (int g = b + 1; g <= NG; g++) gstart[g] = N_NODES;
    } else if (blk == 423) {
        if (t < NB) bucketCur[t] = 0;
        if (t == 0) *done = 0;
    } else {
        float4 zz = {0.f, 0.f, 0.f, 0.f};
#pragma unroll
        for (int j = 0; j < 4; ++j)
            *(float4*)&SP[(j * 256 + t) * 4] = zz;   // 4096 floats
    }
}

// ================= MFMA dual GEMM: xl = A@Wl + bl, xr = A@Wr + br (bf16) =====
// W fragments straight from global (L2-hot). Fused epilogue also emits
// Al[n][h] = 0.6*log2e * att_h . xl[n]  (from f32 accumulators, mat=0 waves).
template<bool AFF, bool BF16IN>
__global__ __launch_bounds__(256) void k_gemm(
    const void* __restrict__ Ain, const unsigned short* __restrict__ Wimg,
    const float* __restrict__ bl, const float* __restrict__ br,
    const float* __restrict__ sc, const float* __restrict__ sh,
    const float* __restrict__ att, float* __restrict__ Al,
    unsigned short* __restrict__ xl, unsigned short* __restrict__ xr, int M)
{
    __shared__ char lds[32768];
    short* As = (short*)lds;             // 16384 B

    int t = threadIdx.x;
    int lane = t & 63;
    int w = t >> 6;
    int brow = blockIdx.x * 64;

    int rl = lane & 15;
    int kh = lane >> 4;
    int mat = w >> 1;
    int c0 = (w & 1) * 64;

    // ---- B fragments from global (issued first, overlap with A staging) ----
    const char* wbase = (const char*)Wimg + mat * 32768;
    bf8_t bfr[4][4];
#pragma unroll
    for (int s = 0; s < 4; ++s)
#pragma unroll
        for (int j = 0; j < 4; ++j)
            bfr[s][j] = *(const bf8_t*)(wbase + (c0 + 16 * j + rl) * 256 + s * 64 + kh * 16);

    // ---- stage A (f32 or packed-bf16 input; optional BN-affine+relu) ----
    {
        int kbase = (t & 7) * 16;
        float scv[16], shv[16];
        if (AFF) {
#pragma unroll
            for (int q = 0; q < 4; ++q) {
                float4 a4 = *(const float4*)&sc[kbase + q * 4];
                float4 b4 = *(const float4*)&sh[kbase + q * 4];
                scv[q*4+0]=a4.x; scv[q*4+1]=a4.y; scv[q*4+2]=a4.z; scv[q*4+3]=a4.w;
                shv[q*4+0]=b4.x; shv[q*4+1]=b4.y; shv[q*4+2]=b4.z; shv[q*4+3]=b4.w;
            }
        }
#pragma unroll
        for (int p = 0; p < 2; ++p) {
            int row = p * 32 + (t >> 3);
            int ar = brow + row; if (ar >= M) ar = M - 1;
            unsigned short vb[16];
            if (BF16IN) {
                const unsigned* src = (const unsigned*)Ain + (size_t)ar * 64 + (kbase >> 1);
                int4 r0 = *(const int4*)src;
                int4 r1 = *(const int4*)(src + 4);
                unsigned ua[8] = {(unsigned)r0.x,(unsigned)r0.y,(unsigned)r0.z,(unsigned)r0.w,
                                  (unsigned)r1.x,(unsigned)r1.y,(unsigned)r1.z,(unsigned)r1.w};
#pragma unroll
                for (int m = 0; m < 8; ++m) {
                    float f0 = __uint_as_float(ua[m] << 16);
                    float f1 = __uint_as_float(ua[m] & 0xFFFF0000u);
                    if (AFF) {
                        f0 = fmaxf(fmaf(f0, scv[2*m], shv[2*m]), 0.f);
                        f1 = fmaxf(fmaf(f1, scv[2*m+1], shv[2*m+1]), 0.f);
                    }
                    vb[2*m] = f2b(f0); vb[2*m+1] = f2b(f1);
                }
            } else {
                const float* src = (const float*)Ain + (size_t)ar * 128 + kbase;
#pragma unroll
                for (int q = 0; q < 4; ++q) {
                    float4 x4 = *(const float4*)&src[q * 4];
                    float vv[4] = {x4.x, x4.y, x4.z, x4.w};
#pragma unroll
                    for (int e = 0; e < 4; ++e) {
                        float f = vv[e];
                        if (AFF) f = fmaxf(fmaf(f, scv[q*4+e], shv[q*4+e]), 0.f);
                        vb[q * 4 + e] = f2b(f);
                    }
                }
            }
            int swz = (row & 7) << 4;
#pragma unroll
            for (int u = 0; u < 2; ++u) {
                int off = (row * 256 + kbase * 2 + u * 16) ^ swz;
                *(int4*)((char*)As + off) = *(int4*)&vb[u * 8];
            }
        }
    }
    __syncthreads();

    // ---- compute ----
    int swz = (rl & 7) << 4;
    f4_t acc[4][4];
#pragma unroll
    for (int i = 0; i < 4; ++i)
#pragma unroll
        for (int j = 0; j < 4; ++j) { f4_t z = {0.f,0.f,0.f,0.f}; acc[i][j] = z; }

    const char* Asc = (const char*)As;
#pragma unroll
    for (int s = 0; s < 4; ++s) {
        int kb2 = (s * 32 + kh * 8) * 2;
        bf8_t af[4];
#pragma unroll
        for (int i = 0; i < 4; ++i) {
            int row = 16 * i + rl;
            af[i] = *(const bf8_t*)(Asc + ((row * 256 + kb2) ^ swz));
        }
#pragma unroll
        for (int i = 0; i < 4; ++i)
#pragma unroll
            for (int j = 0; j < 4; ++j)
                acc[i][j] = __builtin_amdgcn_mfma_f32_16x16x32_bf16(af[i], bfr[s][j], acc[i][j], 0, 0, 0);
    }

    // ---- epilogue ----
    __syncthreads();
    short* Cs = (short*)lds;   // [64][256] bf16, swizzled (32 KB)
    const float* bb = mat ? br : bl;
    float blv[4];
#pragma unroll
    for (int j = 0; j < 4; ++j) blv[j] = bb[c0 + 16 * j + rl];

    // fused Al (source-logit) for xl waves: per-head 32-ch dot via rsum16.
    if (mat == 0) {
        const float sAl = 0.6f * LOG2E;
        float ap0 = att[c0 + rl] * sAl;
        float ap1 = att[c0 + 16 + rl] * sAl;
        float ap2 = att[c0 + 32 + rl] * sAl;
        float ap3 = att[c0 + 48 + rl] * sAl;
        float cl = fmaf(ap0, blv[0], ap1 * blv[1]);
        float ch = fmaf(ap2, blv[2], ap3 * blv[3]);
        int hbase = c0 >> 5;   // 0 (w=0) or 2 (w=1)
#pragma unroll
        for (int i = 0; i < 4; ++i)
#pragma unroll
            for (int q = 0; q < 4; ++q) {
                float pl = fmaf(ap0, acc[i][0][q], fmaf(ap1, acc[i][1][q], cl));
                float ph = fmaf(ap2, acc[i][2][q], fmaf(ap3, acc[i][3][q], ch));
                pl = rsum16(pl);
                ph = rsum16(ph);
                int node = brow + 16 * i + kh * 4 + q;
                if (rl == 0 && node < M) {
                    float2 w2 = make_float2(pl, ph);
                    *(float2*)&Al[(size_t)node * 4 + hbase] = w2;
                }
            }
    }

#pragma unroll
    for (int i = 0; i < 4; ++i)
#pragma unroll
        for (int j = 0; j < 4; ++j) {
            int col = mat * 128 + c0 + 16 * j + rl;
#pragma unroll
            for (int q = 0; q < 4; ++q) {
                int row = 16 * i + kh * 4 + q;
                int off = (row * 512 + col * 2) ^ ((row & 7) << 4);
                *(short*)((char*)Cs + off) = (short)f2b(acc[i][j][q] + blv[j]);
            }
        }
    __syncthreads();
#pragma unroll
    for (int rep = 0; rep < 8; ++rep) {
        int unit = rep * 256 + t;
        int row = unit >> 5;
        int slot = unit & 31;
        int gr = brow + row;
        if (gr < M) {
            int off = (row * 512 + slot * 16) ^ ((row & 7) << 4);
            int4 vv = *(const int4*)((char*)Cs + off);
            unsigned short* O = (slot < 16) ? xl : xr;
            int gcol = (slot & 15) * 8;
            *(int4*)&O[(size_t)gr * 128 + gcol] = vv;
        }
    }
}

// ===== fused edge softmax + aggregation + BN stats + last-block BN finalize ==
__global__ __launch_bounds__(256) void k_agg(
    const unsigned* __restrict__ xl, const unsigned* __restrict__ xr,
    const int* __restrict__ startA, const int* __restrict__ cntA,
    const unsigned* __restrict__ colB,
    const float* __restrict__ att, const float* __restrict__ bias,
    const float* __restrict__ Al, unsigned* __restrict__ hout,
    float* __restrict__ SP, int* __restrict__ done,
    const float* __restrict__ g, const float* __restrict__ be,
    float* __restrict__ sc, float* __restrict__ sh)
{
    int tid = threadIdx.x;
    int lane = tid & 63;
    int wv = tid >> 6;
    int n = blockIdx.x * 4 + wv;
    int e = lane >> 4;                 // edge slot 0..3
    int hq = lane & 15;                // h*4+q
    int h4 = (hq >> 2) * 4;            // byte offset of head in Al row
    unsigned hq16 = (unsigned)hq * 16u;
    const char* xlb = (const char*)xl;
    const char* alb = (const char*)Al;

    // att' slice (8 ch of this head-quarter), pre-scaled by 0.4*log2e
    float ap[8];
    {
        float4 q0 = *(const float4*)&att[hq * 8];
        float4 q1 = *(const float4*)&att[hq * 8 + 4];
        const float s = 0.4f * LOG2E;
        ap[0]=q0.x*s; ap[1]=q0.y*s; ap[2]=q0.z*s; ap[3]=q0.w*s;
        ap[4]=q1.x*s; ap[5]=q1.y*s; ap[6]=q1.z*s; ap[7]=q1.w*s;
    }
    // xr slice for this node
    float zx[8];
    {
        int4 xru = *(const int4*)((const char*)xr + (size_t)n * 256 + hq16);
        unpack8(xru, zx);
    }
    // Snode = 0.6*log2e * att_h . xr[n]  (= 1.5 * quadsum(dot(ap, zx)))
    float arp = ap[0] * zx[0];
#pragma unroll
    for (int c = 1; c < 8; ++c) arp = fmaf(ap[c], zx[c], arp);
    float Snode = 1.5f * quadsum(arp);

    int a0i = startA[n];
    int cn = cntA[n];                  // >= 1 (self loop)
    int nb = (cn + 3) >> 2;

    // pipeline prologue (bucket tail pads zeroed -> stray reads hit node 0,
    // masked out by wg)
    unsigned off0 = colB[a0i + e];
    float al0 = *(const float*)(alb + ((off0 >> 4) & ~15u) + h4);
    int4 d0 = *(const int4*)(xlb + off0 + hq16);
    unsigned off1 = off0;
    if (nb > 1) off1 = colB[a0i + 4 + e];

    float acc[8] = {0.f,0.f,0.f,0.f,0.f,0.f,0.f,0.f};
    float wsum = 0.f;

    for (int b = 0; b < nb; ++b) {
        unsigned off2 = off1;
        if (b + 2 < nb) off2 = colB[a0i + (b + 2) * 4 + e];
        float al1 = al0; int4 d1 = d0;
        if (b + 1 < nb) {
            al1 = *(const float*)(alb + ((off1 >> 4) & ~15u) + h4);
            d1 = *(const int4*)(xlb + off1 + hq16);
        }
        float z[8]; unpack8(d0, z);
        float t0 = z[0] + zx[0];
        float D = ap[0] * fabsf(t0);
#pragma unroll
        for (int c = 1; c < 8; ++c) {
            float tc = z[c] + zx[c];
            D = fmaf(ap[c], fabsf(tc), D);
        }
        D = quadsum(D);
        float wg = exp2f(al0 + Snode + D);
        if (b == nb - 1) wg = (b * 4 + e < cn) ? wg : 0.f;   // tail mask
#pragma unroll
        for (int c = 0; c < 8; ++c) acc[c] = fmaf(wg, z[c], acc[c]);
        wsum += wg;
        off0 = off1; off1 = off2; al0 = al1; d0 = d1;
    }

    // reduce across the 4 edge groups (lanes xor 16, 32)
#pragma unroll
    for (int c = 0; c < 8; ++c) {
        acc[c] += __shfl_xor(acc[c], 16, 64);
        acc[c] += __shfl_xor(acc[c], 32, 64);
    }
    wsum += __shfl_xor(wsum, 16, 64);
    wsum += __shfl_xor(wsum, 32, 64);

    float inv = 1.f / wsum;
    float4 b0 = *(const float4*)&bias[hq * 8];
    float4 b1 = *(const float4*)&bias[hq * 8 + 4];
    float bv[8] = {b0.x,b0.y,b0.z,b0.w,b1.x,b1.y,b1.z,b1.w};
    float ov[8];
    unsigned r[4];
#pragma unroll
    for (int k = 0; k < 4; ++k) {
        float o0 = fmaf(acc[2*k],     inv, bv[2*k]);
        float o1 = fmaf(acc[2*k + 1], inv, bv[2*k + 1]);
        ov[2*k] = o0; ov[2*k+1] = o1;
        r[k] = (unsigned)f2b(o0) | ((unsigned)f2b(o1) << 16);
    }

    // BN stats: per-node (lane<16 holds the 128 channels, 8 each)
    __shared__ float sO[4][128], sQ[4][128];
    if (lane < 16) {
        *(int4*)((char*)hout + (size_t)n * 256 + hq16) = *(int4*)r;
#pragma unroll
        for (int c = 0; c < 8; ++c) {
            sO[wv][hq * 8 + c] = ov[c];
            sQ[wv][hq * 8 + c] = ov[c] * ov[c];
        }
    }
    __syncthreads();
    if (tid < 128) {
        float s = sO[0][tid] + sO[1][tid] + sO[2][tid] + sO[3][tid];
        float q = sQ[0][tid] + sQ[1][tid] + sQ[2][tid] + sQ[3][tid];
        float* slot = SP + (size_t)(blockIdx.x & (NSLOT - 1)) * 256;
        atomicAdd(&slot[tid], s);
        atomicAdd(&slot[128 + tid], q);
    }

    // ---- last-block BN finalize (device-scope atomics; exch = read+rezero) --
    __shared__ int lastFlag;
    __syncthreads();
    if (tid == 0) {
        __threadfence();
        lastFlag = (atomicAdd(done, 1) == NAGG - 1);
    }
    __syncthreads();
    if (lastFlag) {
        int c = tid & 127, half = tid >> 7;
        float v = 0.f;
#pragma unroll
        for (int j = 0; j < NSLOT; ++j)
            v += atomicExch(&SP[j * 256 + half * 128 + c], 0.f);
        __shared__ float fin[256];
        fin[tid] = v;
        __syncthreads();
        if (tid < 128) {
            float s = fin[tid], q = fin[128 + tid];
            float mu = s * (1.f / N_NODES);
            float var = q * (1.f / N_NODES) - mu * mu;
            float sv = rsqrtf(var + EPS_BN) * g[tid];
            sc[tid] = sv;
            sh[tid] = be[tid] - mu * sv;
        }
        if (tid == 0) atomicExch(done, 0);
    }
}

// ====== tail: per-graph mean pool (BN2 affine+relu fused) + MLP head ========
__global__ __launch_bounds__(256) void k_tail(
    const unsigned* __restrict__ h, const int* __restrict__ gstart,
    const float* __restrict__ gf,
    const float* __restrict__ sc, const float* __restrict__ sh,
    const float* __restrict__ W1, const float* __restrict__ b1,
    const float* __restrict__ W2, const float* __restrict__ b2,
    float* __restrict__ out)
{
    int g = blockIdx.x;
    int t = threadIdx.x;
    int wv = t >> 6;
    int lane = t & 63;
    int c0 = lane * 2;

    float sc0 = sc[c0], sc1 = sc[c0 + 1], sh0 = sh[c0], sh1 = sh[c0 + 1];
    int r0 = gstart[g], r1 = gstart[g + 1];
    float s0 = 0.f, s1 = 0.f;
    for (int r = r0 + wv; r < r1; r += 4) {
        unsigned u = h[(size_t)r * 64 + lane];
        float v0 = __uint_as_float(u << 16);
        float v1 = __uint_as_float(u & 0xFFFF0000u);
        s0 += fmaxf(fmaf(v0, sc0, sh0), 0.f);
        s1 += fmaxf(fmaf(v1, sc1, sh1), 0.f);
    }
    __shared__ float sP[4][128];
    sP[wv][c0] = s0;
    sP[wv][c0 + 1] = s1;
    __syncthreads();

    __shared__ float zs[160];
    __shared__ float red[4];
    float invc = 1.f / fmaxf((float)(r1 - r0), 1.f);
    if (t < 128)
        zs[t] = (sP[0][t] + sP[1][t] + sP[2][t] + sP[3][t]) * invc;
    else if (t < 160)
        zs[t] = gf[(size_t)g * 32 + (t - 128)];
    __syncthreads();

    float acc = b1[t];
#pragma unroll 8
    for (int i = 0; i < 160; i++) acc = fmaf(zs[i], W1[i * 256 + t], acc);
    acc = fmaxf(acc, 0.f);
    float part = acc * W2[t];
    part += __shfl_xor(part, 32, 64);
    part += __shfl_xor(part, 16, 64);
    part += __shfl_xor(part, 8, 64);
    part += __shfl_xor(part, 4, 64);
    part += __shfl_xor(part, 2, 64);
    part += __shfl_xor(part, 1, 64);
    if ((t & 63) == 0) red[t >> 6] = part;
    __syncthreads();
    if (t == 0) out[g] = red[0] + red[1] + red[2] + red[3] + b2[0];
}

extern "C" void kernel_launch(void* const* d_in, const int* in_sizes, int n_in,
                              void* d_out, int out_size, void* d_ws, size_t ws_size,
                              hipStream_t stream) {
    (void)in_sizes; (void)n_in; (void)out_size; (void)ws_size;

    const float* x     = (const float*)d_in[0];
    const int*   ei    = (const int*)d_in[1];
    const int*   batch = (const int*)d_in[2];
    const float* gf    = (const float*)d_in[3];
    const float* Wl1 = (const float*)d_in[4];
    const float* bl1 = (const float*)d_in[5];
    const float* Wr1 = (const float*)d_in[6];
    const float* br1 = (const float*)d_in[7];
    const float* att1  = (const float*)d_in[8];
    const float* bias1 = (const float*)d_in[9];
    const float* g1  = (const float*)d_in[10];
    const float* be1 = (const float*)d_in[11];
    const float* Wl2 = (const float*)d_in[12];
    const float* bl2 = (const float*)d_in[13];
    const float* Wr2 = (const float*)d_in[14];
    const float* br2 = (const float*)d_in[15];
    const float* att2  = (const float*)d_in[16];
    const float* bias2 = (const float*)d_in[17];
    const float* g2  = (const float*)d_in[18];
    const float* be2 = (const float*)d_in[19];
    const float* Wfc1 = (const float*)d_in[20];
    const float* bfc1 = (const float*)d_in[21];
    const float* Wfc2 = (const float*)d_in[22];
    const float* bfc2 = (const float*)d_in[23];
    float* out = (float*)d_out;

    char* ws = (char*)d_ws;
    unsigned short* xl = (unsigned short*)(ws + 0);            // 25.6 MB bf16
    unsigned short* xr = (unsigned short*)(ws + 25600000);     // 25.6 MB bf16
    unsigned* h     = (unsigned*)(ws + 51200000);              // 25.6 MB bf16 packed
    int*   colA     = (int*)(ws + 76800000);                   // 9.63 MB (bucketed)
    int*   bktBuf   = (int*)(ws + 86434560);                   // 9.63 MB packed ints
    int*   bucketCur= (int*)(ws + 96068608);                   // 1 KB
    float* SP       = (float*)(ws + 96069632);                 // 16 KB (16 slots)
    int*   done     = (int*)(ws + 96086016);                   // 8 B
    int*   cntA     = (int*)(ws + 96086272);                   // 400 KB
    int*   startA   = (int*)(ws + 96486272);                   // 400 KB
    float* scsh     = (float*)(ws + 96886272);                 // 2 KB: sc1|sh1|sc2|sh2
    int*   gstart   = (int*)(ws + 96888320);                   // 4.1 KB
    unsigned short* Wimg1 = (unsigned short*)(ws + 96892928);  // 64 KB
    unsigned short* Wimg2 = (unsigned short*)(ws + 96958464);  // 64 KB
    float* Al       = (float*)(ws + 97024000);                 // 1.6 MB [N][4]

    // prep (W images, graph bounds, zero bucketCur/SP/done) + CSR build
    k_prep<<<425, 256, 0, stream>>>(Wl1, Wr1, Wl2, Wr2, Wimg1, Wimg2,
                                    batch, gstart, bucketCur, SP, done);
    k_part<<<(EP + 4095) / 4096, 256, 0, stream>>>(ei, bucketCur, bktBuf);
    k_build<<<NB, 512, 0, stream>>>(bktBuf, bucketCur, startA, cntA, colA);

    int gemm_grid = (N_NODES + 63) / 64;

    // Layer 1
    k_gemm<false, false><<<gemm_grid, 256, 0, stream>>>(x, Wimg1, bl1, br1,
                                                        nullptr, nullptr, att1, Al,
                                                        xl, xr, N_NODES);
    k_agg<<<NAGG, 256, 0, stream>>>((const unsigned*)xl, (const unsigned*)xr,
                                    startA, cntA, (const unsigned*)colA,
                                    att1, bias1, Al, h, SP, done,
                                    g1, be1, scsh + 0, scsh + 128);

    // Layer 2 (BN1 apply + ReLU fused into GEMM A-staging, bf16 input)
    k_gemm<true, true><<<gemm_grid, 256, 0, stream>>>(h, Wimg2, bl2, br2,
                                                      scsh + 0, scsh + 128, att2, Al,
                                                      xl, xr, N_NODES);
    k_agg<<<NAGG, 256, 0, stream>>>((const unsigned*)xl, (const unsigned*)xr,
                                    startA, cntA, (const unsigned*)colA,
                                    att2, bias2, Al, h, SP, done,
                                    g2, be2, scsh + 256, scsh + 384);

    // Tail: pool (BN2 affine+relu fused) + MLP, one launch
    k_tail<<<NG, 256, 0, stream>>>(h, gstart, gf, scsh + 256, scsh + 384,
                                   Wfc1, bfc1, Wfc2, bfc2, out);
}

// Round 14
// 732.653 us; speedup vs baseline: 2.5008x; 2.5008x over previous
//
#include <hip/hip_runtime.h>

#define N_NODES 100000
#define E_EDGES 1600000
#define EP (E_EDGES + N_NODES)
#define NG 1024
#define NEG 0.2f
#define EPS_BN 1e-5f
#define LOG2E 1.44269504088896f

#define NB 196        // dst buckets of 512 nodes
#define BCAP 12288    // per-bucket capacity (mean 8704)
#define NAGG (N_NODES / 4)   // k_agg grid
#define NSLOT 16      // BN partial slots

typedef __attribute__((ext_vector_type(8))) short bf8_t;
typedef __attribute__((ext_vector_type(4))) float f4_t;

__device__ __forceinline__ unsigned short f2b(float f) {   // f32 -> bf16 RNE
    unsigned u = __float_as_uint(f);
    u += 0x7FFF + ((u >> 16) & 1);
    return (unsigned short)(u >> 16);
}

// 16-lane sum via mov_dpp row_ror butterfly; result broadcast to 16 lanes.
__device__ __forceinline__ float rsum16(float p) {
    p += __int_as_float(__builtin_amdgcn_mov_dpp(__float_as_int(p), 0x128, 0xf, 0xf, true));
    p += __int_as_float(__builtin_amdgcn_mov_dpp(__float_as_int(p), 0x124, 0xf, 0xf, true));
    p += __int_as_float(__builtin_amdgcn_mov_dpp(__float_as_int(p), 0x122, 0xf, 0xf, true));
    p += __int_as_float(__builtin_amdgcn_mov_dpp(__float_as_int(p), 0x121, 0xf, 0xf, true));
    return p;
}

// 4-lane (quad) sum via quad_perm DPP; result broadcast to all 4 lanes.
__device__ __forceinline__ float quadsum(float p) {
    p += __int_as_float(__builtin_amdgcn_mov_dpp(__float_as_int(p), 0xB1, 0xf, 0xf, true)); // [1,0,3,2]
    p += __int_as_float(__builtin_amdgcn_mov_dpp(__float_as_int(p), 0x4E, 0xf, 0xf, true)); // [2,3,0,1]
    return p;
}

__device__ __forceinline__ void unpack8(const int4& d, float* z) {
    unsigned a = (unsigned)d.x, b = (unsigned)d.y, c = (unsigned)d.z, w = (unsigned)d.w;
    z[0] = __uint_as_float(a << 16); z[1] = __uint_as_float(a & 0xFFFF0000u);
    z[2] = __uint_as_float(b << 16); z[3] = __uint_as_float(b & 0xFFFF0000u);
    z[4] = __uint_as_float(c << 16); z[5] = __uint_as_float(c & 0xFFFF0000u);
    z[6] = __uint_as_float(w << 16); z[7] = __uint_as_float(w & 0xFFFF0000u);
}

// ================= CSR build: partition -> per-bucket build (packed int) =====
// buf entry = (src << 9) | (dst & 511); bucket = dst >> 9.
__global__ __launch_bounds__(256) void k_part(const int* __restrict__ ei,
                                              int* __restrict__ bucketCur,
                                              int* __restrict__ buf) {
    __shared__ int lh[NB], lb[NB];
    int t = threadIdx.x;
    for (int i = t; i < NB; i += 256) lh[i] = 0;
    __syncthreads();
    int base = blockIdx.x * 4096;
    int pk[16];
    int bk[16];
    int rk[16];
#pragma unroll
    for (int i = 0; i < 16; i++) {
        int idx = base + i * 256 + t;
        int s, d;
        if (idx < E_EDGES) { s = ei[idx]; d = ei[E_EDGES + idx]; }
        else if (idx < EP) { s = d = idx - E_EDGES; }
        else { s = 0; d = -1; }
        pk[i] = (s << 9) | (d & 511);
        bk[i] = d >> 9;
        rk[i] = (d >= 0) ? atomicAdd(&lh[d >> 9], 1) : 0;
    }
    __syncthreads();
    for (int i = t; i < NB; i += 256) lb[i] = atomicAdd(&bucketCur[i], lh[i]);
    __syncthreads();
#pragma unroll
    for (int i = 0; i < 16; i++) {
        int bkt = bk[i];
        if (bkt >= 0)
            buf[(size_t)bkt * BCAP + lb[bkt] + rk[i]] = pk[i];
    }
}

// per-bucket: histogram -> LDS scan -> startA/cntA -> place colA (byte offsets)
// + zero a 16-int tail pad after each bucket's used region (pipeline over-reads)
__global__ __launch_bounds__(512) void k_build(const int* __restrict__ buf,
                                               const int* __restrict__ bcnt,
                                               int* __restrict__ startA,
                                               int* __restrict__ cntA,
                                               int* __restrict__ colA) {
    __shared__ int h[512];
    __shared__ int s[512];
    int b = blockIdx.x, t = threadIdx.x;
    h[t] = 0;
    __syncthreads();
    int n = bcnt[b];
    const int* p = buf + (size_t)b * BCAP;
    for (int i = t; i < n; i += 512) atomicAdd(&h[p[i] & 511], 1);
    __syncthreads();
    int v = h[t];
    s[t] = v;
    __syncthreads();
    for (int o = 1; o < 512; o <<= 1) {
        int u = (t >= o) ? s[t - o] : 0;
        __syncthreads();
        s[t] += u;
        __syncthreads();
    }
    int myStart = b * BCAP + s[t] - v;   // exclusive prefix within bucket
    int node = (b << 9) + t;
    if (node < N_NODES) {
        startA[node] = myStart;
        cntA[node] = v;
    }
    h[t] = myStart;                      // reuse as running cursor
    __syncthreads();
    for (int i = t; i < n; i += 512) {
        int e = p[i];
        int r = atomicAdd(&h[e & 511], 1);
        colA[r] = (e >> 9) << 8;         // src * 256 (byte offset into xl)
    }
    if (t < 16) colA[b * BCAP + n + t] = 0;   // tail pad (stray reads -> node 0)
}

// === prep: wconv L1+L2 (blocks 0..31) + gstart (32..422) + zero (423..424) ===
__global__ __launch_bounds__(256) void k_prep(
    const float* __restrict__ Wl1, const float* __restrict__ Wr1,
    const float* __restrict__ Wl2, const float* __restrict__ Wr2,
    unsigned short* __restrict__ img1, unsigned short* __restrict__ img2,
    const int* __restrict__ batch, int* __restrict__ gstart,
    int* __restrict__ bucketCur, float* __restrict__ SP, int* __restrict__ done) {
    int blk = blockIdx.x;
    int t = threadIdx.x;
    if (blk < 32) {
        int lay = blk >> 4;
        int g = (blk & 15) * 256 + t;   // 4096 chunks per layer
        int m = g >> 11, n = (g >> 4) & 127, kb = g & 15;
        const float* W = lay ? (m ? Wr2 : Wl2) : (m ? Wr1 : Wl1);
        unsigned short* img = lay ? img2 : img1;
        unsigned short v[8];
#pragma unroll
        for (int j = 0; j < 8; j++) v[j] = f2b(W[(kb * 8 + j) * 128 + n]);
        int off = m * 32768 + n * 256 + kb * 16;
        *(int4*)((char*)img + off) = *(int4*)v;
    } else if (blk < 423) {
        int i = (blk - 32) * 256 + t;
        if (i >= N_NODES) return;
        int b = batch[i];
        int prev = (i == 0) ? -1 : batch[i - 1];
        for (int g = prev + 1; g <= b; g++) gstart[g] = i;
        if (i == N_NODES - 1)
            for (int g = b + 1; g <= NG; g++) gstart[g] = N_NODES;
    } else if (blk == 423) {
        if (t < NB) bucketCur[t] = 0;
        if (t == 0) *done = 0;
    } else {
        float4 zz = {0.f, 0.f, 0.f, 0.f};
#pragma unroll
        for (int j = 0; j < 4; ++j)
            *(float4*)&SP[(j * 256 + t) * 4] = zz;   // 4096 floats
    }
}

// ================= MFMA dual GEMM: xl = A@Wl + bl, xr = A@Wr + br (bf16) =====
// W fragments straight from global (L2-hot). Fused epilogue also emits
// Al[n][h] = 0.6*log2e * att_h . xl[n]  (from f32 accumulators, mat=0 waves).
template<bool AFF, bool BF16IN>
__global__ __launch_bounds__(256) void k_gemm(
    const void* __restrict__ Ain, const unsigned short* __restrict__ Wimg,
    const float* __restrict__ bl, const float* __restrict__ br,
    const float* __restrict__ sc, const float* __restrict__ sh,
    const float* __restrict__ att, float* __restrict__ Al,
    unsigned short* __restrict__ xl, unsigned short* __restrict__ xr, int M)
{
    __shared__ char lds[32768];
    short* As = (short*)lds;             // 16384 B

    int t = threadIdx.x;
    int lane = t & 63;
    int w = t >> 6;
    int brow = blockIdx.x * 64;

    int rl = lane & 15;
    int kh = lane >> 4;
    int mat = w >> 1;
    int c0 = (w & 1) * 64;

    // ---- B fragments from global (issued first, overlap with A staging) ----
    const char* wbase = (const char*)Wimg + mat * 32768;
    bf8_t bfr[4][4];
#pragma unroll
    for (int s = 0; s < 4; ++s)
#pragma unroll
        for (int j = 0; j < 4; ++j)
            bfr[s][j] = *(const bf8_t*)(wbase + (c0 + 16 * j + rl) * 256 + s * 64 + kh * 16);

    // ---- stage A (f32 or packed-bf16 input; optional BN-affine+relu) ----
    {
        int kbase = (t & 7) * 16;
        float scv[16], shv[16];
        if (AFF) {
#pragma unroll
            for (int q = 0; q < 4; ++q) {
                float4 a4 = *(const float4*)&sc[kbase + q * 4];
                float4 b4 = *(const float4*)&sh[kbase + q * 4];
                scv[q*4+0]=a4.x; scv[q*4+1]=a4.y; scv[q*4+2]=a4.z; scv[q*4+3]=a4.w;
                shv[q*4+0]=b4.x; shv[q*4+1]=b4.y; shv[q*4+2]=b4.z; shv[q*4+3]=b4.w;
            }
        }
#pragma unroll
        for (int p = 0; p < 2; ++p) {
            int row = p * 32 + (t >> 3);
            int ar = brow + row; if (ar >= M) ar = M - 1;
            unsigned short vb[16];
            if (BF16IN) {
                const unsigned* src = (const unsigned*)Ain + (size_t)ar * 64 + (kbase >> 1);
                int4 r0 = *(const int4*)src;
                int4 r1 = *(const int4*)(src + 4);
                unsigned ua[8] = {(unsigned)r0.x,(unsigned)r0.y,(unsigned)r0.z,(unsigned)r0.w,
                                  (unsigned)r1.x,(unsigned)r1.y,(unsigned)r1.z,(unsigned)r1.w};
#pragma unroll
                for (int m = 0; m < 8; ++m) {
                    float f0 = __uint_as_float(ua[m] << 16);
                    float f1 = __uint_as_float(ua[m] & 0xFFFF0000u);
                    if (AFF) {
                        f0 = fmaxf(fmaf(f0, scv[2*m], shv[2*m]), 0.f);
                        f1 = fmaxf(fmaf(f1, scv[2*m+1], shv[2*m+1]), 0.f);
                    }
                    vb[2*m] = f2b(f0); vb[2*m+1] = f2b(f1);
                }
            } else {
                const float* src = (const float*)Ain + (size_t)ar * 128 + kbase;
#pragma unroll
                for (int q = 0; q < 4; ++q) {
                    float4 x4 = *(const float4*)&src[q * 4];
                    float vv[4] = {x4.x, x4.y, x4.z, x4.w};
#pragma unroll
                    for (int e = 0; e < 4; ++e) {
                        float f = vv[e];
                        if (AFF) f = fmaxf(fmaf(f, scv[q*4+e], shv[q*4+e]), 0.f);
                        vb[q * 4 + e] = f2b(f);
                    }
                }
            }
            int swz = (row & 7) << 4;
#pragma unroll
            for (int u = 0; u < 2; ++u) {
                int off = (row * 256 + kbase * 2 + u * 16) ^ swz;
                *(int4*)((char*)As + off) = *(int4*)&vb[u * 8];
            }
        }
    }
    __syncthreads();

    // ---- compute ----
    int swz = (rl & 7) << 4;
    f4_t acc[4][4];
#pragma unroll
    for (int i = 0; i < 4; ++i)
#pragma unroll
        for (int j = 0; j < 4; ++j) { f4_t z = {0.f,0.f,0.f,0.f}; acc[i][j] = z; }

    const char* Asc = (const char*)As;
#pragma unroll
    for (int s = 0; s < 4; ++s) {
        int kb2 = (s * 32 + kh * 8) * 2;
        bf8_t af[4];
#pragma unroll
        for (int i = 0; i < 4; ++i) {
            int row = 16 * i + rl;
            af[i] = *(const bf8_t*)(Asc + ((row * 256 + kb2) ^ swz));
        }
#pragma unroll
        for (int i = 0; i < 4; ++i)
#pragma unroll
            for (int j = 0; j < 4; ++j)
                acc[i][j] = __builtin_amdgcn_mfma_f32_16x16x32_bf16(af[i], bfr[s][j], acc[i][j], 0, 0, 0);
    }

    // ---- epilogue ----
    __syncthreads();
    short* Cs = (short*)lds;   // [64][256] bf16, swizzled (32 KB)
    const float* bb = mat ? br : bl;
    float blv[4];
#pragma unroll
    for (int j = 0; j < 4; ++j) blv[j] = bb[c0 + 16 * j + rl];

    // fused Al (source-logit) for xl waves: per-head 32-ch dot via rsum16.
    if (mat == 0) {
        const float sAl = 0.6f * LOG2E;
        float ap0 = att[c0 + rl] * sAl;
        float ap1 = att[c0 + 16 + rl] * sAl;
        float ap2 = att[c0 + 32 + rl] * sAl;
        float ap3 = att[c0 + 48 + rl] * sAl;
        float cl = fmaf(ap0, blv[0], ap1 * blv[1]);
        float ch = fmaf(ap2, blv[2], ap3 * blv[3]);
        int hbase = c0 >> 5;   // 0 (w=0) or 2 (w=1)
#pragma unroll
        for (int i = 0; i < 4; ++i)
#pragma unroll
            for (int q = 0; q < 4; ++q) {
                float pl = fmaf(ap0, acc[i][0][q], fmaf(ap1, acc[i][1][q], cl));
                float ph = fmaf(ap2, acc[i][2][q], fmaf(ap3, acc[i][3][q], ch));
                pl = rsum16(pl);
                ph = rsum16(ph);
                int node = brow + 16 * i + kh * 4 + q;
                if (rl == 0 && node < M) {
                    float2 w2 = make_float2(pl, ph);
                    *(float2*)&Al[(size_t)node * 4 + hbase] = w2;
                }
            }
    }

#pragma unroll
    for (int i = 0; i < 4; ++i)
#pragma unroll
        for (int j = 0; j < 4; ++j) {
            int col = mat * 128 + c0 + 16 * j + rl;
#pragma unroll
            for (int q = 0; q < 4; ++q) {
                int row = 16 * i + kh * 4 + q;
                int off = (row * 512 + col * 2) ^ ((row & 7) << 4);
                *(short*)((char*)Cs + off) = (short)f2b(acc[i][j][q] + blv[j]);
            }
        }
    __syncthreads();
#pragma unroll
    for (int rep = 0; rep < 8; ++rep) {
        int unit = rep * 256 + t;
        int row = unit >> 5;
        int slot = unit & 31;
        int gr = brow + row;
        if (gr < M) {
            int off = (row * 512 + slot * 16) ^ ((row & 7) << 4);
            int4 vv = *(const int4*)((char*)Cs + off);
            unsigned short* O = (slot < 16) ? xl : xr;
            int gcol = (slot & 15) * 8;
            *(int4*)&O[(size_t)gr * 128 + gcol] = vv;
        }
    }
}

// ===== fused edge softmax + aggregation + BN stats + last-block BN finalize ==
// NO __threadfence here: SP data flows atomics->atomics (L2-coherent, device
// scope by default), and the __syncthreads() before the done-signal already
// drains vmcnt (compiler emits s_waitcnt vmcnt(0) before s_barrier), so each
// block's SP atomics are complete before its done increment. A threadfence
// would emit a per-block L2 writeback (XCD-coherence tax) — round 13 showed
// that costs 10x.
__global__ __launch_bounds__(256) void k_agg(
    const unsigned* __restrict__ xl, const unsigned* __restrict__ xr,
    const int* __restrict__ startA, const int* __restrict__ cntA,
    const unsigned* __restrict__ colB,
    const float* __restrict__ att, const float* __restrict__ bias,
    const float* __restrict__ Al, unsigned* __restrict__ hout,
    float* __restrict__ SP, int* __restrict__ done,
    const float* __restrict__ g, const float* __restrict__ be,
    float* __restrict__ sc, float* __restrict__ sh)
{
    int tid = threadIdx.x;
    int lane = tid & 63;
    int wv = tid >> 6;
    int n = blockIdx.x * 4 + wv;
    int e = lane >> 4;                 // edge slot 0..3
    int hq = lane & 15;                // h*4+q
    int h4 = (hq >> 2) * 4;            // byte offset of head in Al row
    unsigned hq16 = (unsigned)hq * 16u;
    const char* xlb = (const char*)xl;
    const char* alb = (const char*)Al;

    // att' slice (8 ch of this head-quarter), pre-scaled by 0.4*log2e
    float ap[8];
    {
        float4 q0 = *(const float4*)&att[hq * 8];
        float4 q1 = *(const float4*)&att[hq * 8 + 4];
        const float s = 0.4f * LOG2E;
        ap[0]=q0.x*s; ap[1]=q0.y*s; ap[2]=q0.z*s; ap[3]=q0.w*s;
        ap[4]=q1.x*s; ap[5]=q1.y*s; ap[6]=q1.z*s; ap[7]=q1.w*s;
    }
    // xr slice for this node
    float zx[8];
    {
        int4 xru = *(const int4*)((const char*)xr + (size_t)n * 256 + hq16);
        unpack8(xru, zx);
    }
    // Snode = 0.6*log2e * att_h . xr[n]  (= 1.5 * quadsum(dot(ap, zx)))
    float arp = ap[0] * zx[0];
#pragma unroll
    for (int c = 1; c < 8; ++c) arp = fmaf(ap[c], zx[c], arp);
    float Snode = 1.5f * quadsum(arp);

    int a0i = startA[n];
    int cn = cntA[n];                  // >= 1 (self loop)
    int nb = (cn + 3) >> 2;

    // pipeline prologue (bucket tail pads zeroed -> stray reads hit node 0,
    // masked out by wg)
    unsigned off0 = colB[a0i + e];
    float al0 = *(const float*)(alb + ((off0 >> 4) & ~15u) + h4);
    int4 d0 = *(const int4*)(xlb + off0 + hq16);
    unsigned off1 = off0;
    if (nb > 1) off1 = colB[a0i + 4 + e];

    float acc[8] = {0.f,0.f,0.f,0.f,0.f,0.f,0.f,0.f};
    float wsum = 0.f;

    for (int b = 0; b < nb; ++b) {
        unsigned off2 = off1;
        if (b + 2 < nb) off2 = colB[a0i + (b + 2) * 4 + e];
        float al1 = al0; int4 d1 = d0;
        if (b + 1 < nb) {
            al1 = *(const float*)(alb + ((off1 >> 4) & ~15u) + h4);
            d1 = *(const int4*)(xlb + off1 + hq16);
        }
        float z[8]; unpack8(d0, z);
        float t0 = z[0] + zx[0];
        float D = ap[0] * fabsf(t0);
#pragma unroll
        for (int c = 1; c < 8; ++c) {
            float tc = z[c] + zx[c];
            D = fmaf(ap[c], fabsf(tc), D);
        }
        D = quadsum(D);
        float wg = exp2f(al0 + Snode + D);
        if (b == nb - 1) wg = (b * 4 + e < cn) ? wg : 0.f;   // tail mask
#pragma unroll
        for (int c = 0; c < 8; ++c) acc[c] = fmaf(wg, z[c], acc[c]);
        wsum += wg;
        off0 = off1; off1 = off2; al0 = al1; d0 = d1;
    }

    // reduce across the 4 edge groups (lanes xor 16, 32)
#pragma unroll
    for (int c = 0; c < 8; ++c) {
        acc[c] += __shfl_xor(acc[c], 16, 64);
        acc[c] += __shfl_xor(acc[c], 32, 64);
    }
    wsum += __shfl_xor(wsum, 16, 64);
    wsum += __shfl_xor(wsum, 32, 64);

    float inv = 1.f / wsum;
    float4 b0 = *(const float4*)&bias[hq * 8];
    float4 b1 = *(const float4*)&bias[hq * 8 + 4];
    float bv[8] = {b0.x,b0.y,b0.z,b0.w,b1.x,b1.y,b1.z,b1.w};
    float ov[8];
    unsigned r[4];
#pragma unroll
    for (int k = 0; k < 4; ++k) {
        float o0 = fmaf(acc[2*k],     inv, bv[2*k]);
        float o1 = fmaf(acc[2*k + 1], inv, bv[2*k + 1]);
        ov[2*k] = o0; ov[2*k+1] = o1;
        r[k] = (unsigned)f2b(o0) | ((unsigned)f2b(o1) << 16);
    }

    // BN stats: per-node (lane<16 holds the 128 channels, 8 each)
    __shared__ float sO[4][128], sQ[4][128];
    if (lane < 16) {
        *(int4*)((char*)hout + (size_t)n * 256 + hq16) = *(int4*)r;
#pragma unroll
        for (int c = 0; c < 8; ++c) {
            sO[wv][hq * 8 + c] = ov[c];
            sQ[wv][hq * 8 + c] = ov[c] * ov[c];
        }
    }
    __syncthreads();
    if (tid < 128) {
        float s = sO[0][tid] + sO[1][tid] + sO[2][tid] + sO[3][tid];
        float q = sQ[0][tid] + sQ[1][tid] + sQ[2][tid] + sQ[3][tid];
        float* slot = SP + (size_t)(blockIdx.x & (NSLOT - 1)) * 256;
        atomicAdd(&slot[tid], s);
        atomicAdd(&slot[128 + tid], q);
    }

    // ---- last-block BN finalize. The barrier below drains vmcnt(0), so all
    // of this block's SP atomics are L2-complete before the done signal. ----
    __shared__ int lastFlag;
    __syncthreads();
    if (tid == 0)
        lastFlag = (atomicAdd(done, 1) == NAGG - 1);
    __syncthreads();
    if (lastFlag) {
        int c = tid & 127, half = tid >> 7;
        float v = 0.f;
#pragma unroll
        for (int j = 0; j < NSLOT; ++j)
            v += atomicExch(&SP[j * 256 + half * 128 + c], 0.f);
        __shared__ float fin[256];
        fin[tid] = v;
        __syncthreads();
        if (tid < 128) {
            float s = fin[tid], q = fin[128 + tid];
            float mu = s * (1.f / N_NODES);
            float var = q * (1.f / N_NODES) - mu * mu;
            float sv = rsqrtf(var + EPS_BN) * g[tid];
            sc[tid] = sv;
            sh[tid] = be[tid] - mu * sv;
        }
        if (tid == 0) atomicExch(done, 0);
    }
}

// ====== tail: per-graph mean pool (BN2 affine+relu fused) + MLP head ========
__global__ __launch_bounds__(256) void k_tail(
    const unsigned* __restrict__ h, const int* __restrict__ gstart,
    const float* __restrict__ gf,
    const float* __restrict__ sc, const float* __restrict__ sh,
    const float* __restrict__ W1, const float* __restrict__ b1,
    const float* __restrict__ W2, const float* __restrict__ b2,
    float* __restrict__ out)
{
    int g = blockIdx.x;
    int t = threadIdx.x;
    int wv = t >> 6;
    int lane = t & 63;
    int c0 = lane * 2;

    float sc0 = sc[c0], sc1 = sc[c0 + 1], sh0 = sh[c0], sh1 = sh[c0 + 1];
    int r0 = gstart[g], r1 = gstart[g + 1];
    float s0 = 0.f, s1 = 0.f;
    for (int r = r0 + wv; r < r1; r += 4) {
        unsigned u = h[(size_t)r * 64 + lane];
        float v0 = __uint_as_float(u << 16);
        float v1 = __uint_as_float(u & 0xFFFF0000u);
        s0 += fmaxf(fmaf(v0, sc0, sh0), 0.f);
        s1 += fmaxf(fmaf(v1, sc1, sh1), 0.f);
    }
    __shared__ float sP[4][128];
    sP[wv][c0] = s0;
    sP[wv][c0 + 1] = s1;
    __syncthreads();

    __shared__ float zs[160];
    __shared__ float red[4];
    float invc = 1.f / fmaxf((float)(r1 - r0), 1.f);
    if (t < 128)
        zs[t] = (sP[0][t] + sP[1][t] + sP[2][t] + sP[3][t]) * invc;
    else if (t < 160)
        zs[t] = gf[(size_t)g * 32 + (t - 128)];
    __syncthreads();

    float acc = b1[t];
#pragma unroll 8
    for (int i = 0; i < 160; i++) acc = fmaf(zs[i], W1[i * 256 + t], acc);
    acc = fmaxf(acc, 0.f);
    float part = acc * W2[t];
    part += __shfl_xor(part, 32, 64);
    part += __shfl_xor(part, 16, 64);
    part += __shfl_xor(part, 8, 64);
    part += __shfl_xor(part, 4, 64);
    part += __shfl_xor(part, 2, 64);
    part += __shfl_xor(part, 1, 64);
    if ((t & 63) == 0) red[t >> 6] = part;
    __syncthreads();
    if (t == 0) out[g] = red[0] + red[1] + red[2] + red[3] + b2[0];
}

extern "C" void kernel_launch(void* const* d_in, const int* in_sizes, int n_in,
                              void* d_out, int out_size, void* d_ws, size_t ws_size,
                              hipStream_t stream) {
    (void)in_sizes; (void)n_in; (void)out_size; (void)ws_size;

    const float* x     = (const float*)d_in[0];
    const int*   ei    = (const int*)d_in[1];
    const int*   batch = (const int*)d_in[2];
    const float* gf    = (const float*)d_in[3];
    const float* Wl1 = (const float*)d_in[4];
    const float* bl1 = (const float*)d_in[5];
    const float* Wr1 = (const float*)d_in[6];
    const float* br1 = (const float*)d_in[7];
    const float* att1  = (const float*)d_in[8];
    const float* bias1 = (const float*)d_in[9];
    const float* g1  = (const float*)d_in[10];
    const float* be1 = (const float*)d_in[11];
    const float* Wl2 = (const float*)d_in[12];
    const float* bl2 = (const float*)d_in[13];
    const float* Wr2 = (const float*)d_in[14];
    const float* br2 = (const float*)d_in[15];
    const float* att2  = (const float*)d_in[16];
    const float* bias2 = (const float*)d_in[17];
    const float* g2  = (const float*)d_in[18];
    const float* be2 = (const float*)d_in[19];
    const float* Wfc1 = (const float*)d_in[20];
    const float* bfc1 = (const float*)d_in[21];
    const float* Wfc2 = (const float*)d_in[22];
    const float* bfc2 = (const float*)d_in[23];
    float* out = (float*)d_out;

    char* ws = (char*)d_ws;
    unsigned short* xl = (unsigned short*)(ws + 0);            // 25.6 MB bf16
    unsigned short* xr = (unsigned short*)(ws + 25600000);     // 25.6 MB bf16
    unsigned* h     = (unsigned*)(ws + 51200000);              // 25.6 MB bf16 packed
    int*   colA     = (int*)(ws + 76800000);                   // 9.63 MB (bucketed)
    int*   bktBuf   = (int*)(ws + 86434560);                   // 9.63 MB packed ints
    int*   bucketCur= (int*)(ws + 96068608);                   // 1 KB
    float* SP       = (float*)(ws + 96069632);                 // 16 KB (16 slots)
    int*   done     = (int*)(ws + 96086016);                   // 8 B
    int*   cntA     = (int*)(ws + 96086272);                   // 400 KB
    int*   startA   = (int*)(ws + 96486272);                   // 400 KB
    float* scsh     = (float*)(ws + 96886272);                 // 2 KB: sc1|sh1|sc2|sh2
    int*   gstart   = (int*)(ws + 96888320);                   // 4.1 KB
    unsigned short* Wimg1 = (unsigned short*)(ws + 96892928);  // 64 KB
    unsigned short* Wimg2 = (unsigned short*)(ws + 96958464);  // 64 KB
    float* Al       = (float*)(ws + 97024000);                 // 1.6 MB [N][4]

    // prep (W images, graph bounds, zero bucketCur/SP/done) + CSR build
    k_prep<<<425, 256, 0, stream>>>(Wl1, Wr1, Wl2, Wr2, Wimg1, Wimg2,
                                    batch, gstart, bucketCur, SP, done);
    k_part<<<(EP + 4095) / 4096, 256, 0, stream>>>(ei, bucketCur, bktBuf);
    k_build<<<NB, 512, 0, stream>>>(bktBuf, bucketCur, startA, cntA, colA);

    int gemm_grid = (N_NODES + 63) / 64;

    // Layer 1
    k_gemm<false, false><<<gemm_grid, 256, 0, stream>>>(x, Wimg1, bl1, br1,
                                                        nullptr, nullptr, att1, Al,
                                                        xl, xr, N_NODES);
    k_agg<<<NAGG, 256, 0, stream>>>((const unsigned*)xl, (const unsigned*)xr,
                                    startA, cntA, (const unsigned*)colA,
                                    att1, bias1, Al, h, SP, done,
                                    g1, be1, scsh + 0, scsh + 128);

    // Layer 2 (BN1 apply + ReLU fused into GEMM A-staging, bf16 input)
    k_gemm<true, true><<<gemm_grid, 256, 0, stream>>>(h, Wimg2, bl2, br2,
                                                      scsh + 0, scsh + 128, att2, Al,
                                                      xl, xr, N_NODES);
    k_agg<<<NAGG, 256, 0, stream>>>((const unsigned*)xl, (const unsigned*)xr,
                                    startA, cntA, (const unsigned*)colA,
                                    att2, bias2, Al, h, SP, done,
                                    g2, be2, scsh + 256, scsh + 384);

    // Tail: pool (BN2 affine+relu fused) + MLP, one launch
    k_tail<<<NG, 256, 0, stream>>>(h, gstart, gf, scsh + 256, scsh + 384,
                                   Wfc1, bfc1, Wfc2, bfc2, out);
}

// Round 15
// 311.590 us; speedup vs baseline: 5.8802x; 2.3513x over previous
//
#include <hip/hip_runtime.h>

#define N_NODES 100000
#define E_EDGES 1600000
#define EP (E_EDGES + N_NODES)
#define NG 1024
#define NEG 0.2f
#define EPS_BN 1e-5f
#define LOG2E 1.44269504088896f

#define NB 196        // dst buckets of 512 nodes
#define BCAP 12288    // per-bucket capacity (mean 8704)
#define NSLOT 64      // BN partial slots (64 -> low same-address contention)

typedef __attribute__((ext_vector_type(8))) short bf8_t;
typedef __attribute__((ext_vector_type(4))) float f4_t;

__device__ __forceinline__ unsigned short f2b(float f) {   // f32 -> bf16 RNE
    unsigned u = __float_as_uint(f);
    u += 0x7FFF + ((u >> 16) & 1);
    return (unsigned short)(u >> 16);
}

// 16-lane sum via mov_dpp row_ror butterfly; result broadcast to 16 lanes.
__device__ __forceinline__ float rsum16(float p) {
    p += __int_as_float(__builtin_amdgcn_mov_dpp(__float_as_int(p), 0x128, 0xf, 0xf, true));
    p += __int_as_float(__builtin_amdgcn_mov_dpp(__float_as_int(p), 0x124, 0xf, 0xf, true));
    p += __int_as_float(__builtin_amdgcn_mov_dpp(__float_as_int(p), 0x122, 0xf, 0xf, true));
    p += __int_as_float(__builtin_amdgcn_mov_dpp(__float_as_int(p), 0x121, 0xf, 0xf, true));
    return p;
}

// 4-lane (quad) sum via quad_perm DPP; result broadcast to all 4 lanes.
__device__ __forceinline__ float quadsum(float p) {
    p += __int_as_float(__builtin_amdgcn_mov_dpp(__float_as_int(p), 0xB1, 0xf, 0xf, true)); // [1,0,3,2]
    p += __int_as_float(__builtin_amdgcn_mov_dpp(__float_as_int(p), 0x4E, 0xf, 0xf, true)); // [2,3,0,1]
    return p;
}

__device__ __forceinline__ void unpack8(const int4& d, float* z) {
    unsigned a = (unsigned)d.x, b = (unsigned)d.y, c = (unsigned)d.z, w = (unsigned)d.w;
    z[0] = __uint_as_float(a << 16); z[1] = __uint_as_float(a & 0xFFFF0000u);
    z[2] = __uint_as_float(b << 16); z[3] = __uint_as_float(b & 0xFFFF0000u);
    z[4] = __uint_as_float(c << 16); z[5] = __uint_as_float(c & 0xFFFF0000u);
    z[6] = __uint_as_float(w << 16); z[7] = __uint_as_float(w & 0xFFFF0000u);
}

// ================= CSR build: partition -> per-bucket build (packed int) =====
// buf entry = (src << 9) | (dst & 511); bucket = dst >> 9.
__global__ __launch_bounds__(256) void k_part(const int* __restrict__ ei,
                                              int* __restrict__ bucketCur,
                                              int* __restrict__ buf) {
    __shared__ int lh[NB], lb[NB];
    int t = threadIdx.x;
    for (int i = t; i < NB; i += 256) lh[i] = 0;
    __syncthreads();
    int base = blockIdx.x * 4096;
    int pk[16];
    int bk[16];
    int rk[16];
#pragma unroll
    for (int i = 0; i < 16; i++) {
        int idx = base + i * 256 + t;
        int s, d;
        if (idx < E_EDGES) { s = ei[idx]; d = ei[E_EDGES + idx]; }
        else if (idx < EP) { s = d = idx - E_EDGES; }
        else { s = 0; d = -1; }
        pk[i] = (s << 9) | (d & 511);
        bk[i] = d >> 9;
        rk[i] = (d >= 0) ? atomicAdd(&lh[d >> 9], 1) : 0;
    }
    __syncthreads();
    for (int i = t; i < NB; i += 256) lb[i] = atomicAdd(&bucketCur[i], lh[i]);
    __syncthreads();
#pragma unroll
    for (int i = 0; i < 16; i++) {
        int bkt = bk[i];
        if (bkt >= 0)
            buf[(size_t)bkt * BCAP + lb[bkt] + rk[i]] = pk[i];
    }
}

// per-bucket: histogram -> LDS scan -> startA/cntA -> place colA (byte offsets)
// + zero a 16-int tail pad after each bucket's used region (pipeline over-reads)
__global__ __launch_bounds__(512) void k_build(const int* __restrict__ buf,
                                               const int* __restrict__ bcnt,
                                               int* __restrict__ startA,
                                               int* __restrict__ cntA,
                                               int* __restrict__ colA) {
    __shared__ int h[512];
    __shared__ int s[512];
    int b = blockIdx.x, t = threadIdx.x;
    h[t] = 0;
    __syncthreads();
    int n = bcnt[b];
    const int* p = buf + (size_t)b * BCAP;
    for (int i = t; i < n; i += 512) atomicAdd(&h[p[i] & 511], 1);
    __syncthreads();
    int v = h[t];
    s[t] = v;
    __syncthreads();
    for (int o = 1; o < 512; o <<= 1) {
        int u = (t >= o) ? s[t - o] : 0;
        __syncthreads();
        s[t] += u;
        __syncthreads();
    }
    int myStart = b * BCAP + s[t] - v;   // exclusive prefix within bucket
    int node = (b << 9) + t;
    if (node < N_NODES) {
        startA[node] = myStart;
        cntA[node] = v;
    }
    h[t] = myStart;                      // reuse as running cursor
    __syncthreads();
    for (int i = t; i < n; i += 512) {
        int e = p[i];
        int r = atomicAdd(&h[e & 511], 1);
        colA[r] = (e >> 9) << 8;         // src * 256 (byte offset into xl)
    }
    if (t < 16) colA[b * BCAP + n + t] = 0;   // tail pad (stray reads -> node 0)
}

// === prep: wconv L1+L2 (blocks 0..31) + gstart (32..422) + zero (423..424) ===
__global__ __launch_bounds__(256) void k_prep(
    const float* __restrict__ Wl1, const float* __restrict__ Wr1,
    const float* __restrict__ Wl2, const float* __restrict__ Wr2,
    unsigned short* __restrict__ img1, unsigned short* __restrict__ img2,
    const int* __restrict__ batch, int* __restrict__ gstart,
    int* __restrict__ bucketCur, float* __restrict__ SP) {
    int blk = blockIdx.x;
    int t = threadIdx.x;
    if (blk < 32) {
        int lay = blk >> 4;
        int g = (blk & 15) * 256 + t;   // 4096 chunks per layer
        int m = g >> 11, n = (g >> 4) & 127, kb = g & 15;
        const float* W = lay ? (m ? Wr2 : Wl2) : (m ? Wr1 : Wl1);
        unsigned short* img = lay ? img2 : img1;
        unsigned short v[8];
#pragma unroll
        for (int j = 0; j < 8; j++) v[j] = f2b(W[(kb * 8 + j) * 128 + n]);
        int off = m * 32768 + n * 256 + kb * 16;
        *(int4*)((char*)img + off) = *(int4*)v;
    } else if (blk < 423) {
        int i = (blk - 32) * 256 + t;
        if (i >= N_NODES) return;
        int b = batch[i];
        int prev = (i == 0) ? -1 : batch[i - 1];
        for (int g = prev + 1; g <= b; g++) gstart[g] = i;
        if (i == N_NODES - 1)
            for (int g = b + 1; g <= NG; g++) gstart[g] = N_NODES;
    } else if (blk == 423) {
        if (t < NB) bucketCur[t] = 0;
    } else {
        // zero SP: NSLOT*256 floats = 16384 floats = 64 KB
        float4 zz = {0.f, 0.f, 0.f, 0.f};
#pragma unroll
        for (int j = 0; j < 16; ++j)
            *(float4*)&SP[(j * 256 + t) * 4] = zz;
    }
}

// ================= MFMA dual GEMM: xl = A@Wl + bl, xr = A@Wr + br (bf16) =====
// W fragments straight from global (L2-hot). Fused epilogue also emits
// Al[n][h] = 0.6*log2e * att_h . xl[n]  (from f32 accumulators, mat=0 waves).
template<bool AFF, bool BF16IN>
__global__ __launch_bounds__(256) void k_gemm(
    const void* __restrict__ Ain, const unsigned short* __restrict__ Wimg,
    const float* __restrict__ bl, const float* __restrict__ br,
    const float* __restrict__ sc, const float* __restrict__ sh,
    const float* __restrict__ att, float* __restrict__ Al,
    unsigned short* __restrict__ xl, unsigned short* __restrict__ xr, int M)
{
    __shared__ char lds[32768];
    short* As = (short*)lds;             // 16384 B

    int t = threadIdx.x;
    int lane = t & 63;
    int w = t >> 6;
    int brow = blockIdx.x * 64;

    int rl = lane & 15;
    int kh = lane >> 4;
    int mat = w >> 1;
    int c0 = (w & 1) * 64;

    // ---- B fragments from global (issued first, overlap with A staging) ----
    const char* wbase = (const char*)Wimg + mat * 32768;
    bf8_t bfr[4][4];
#pragma unroll
    for (int s = 0; s < 4; ++s)
#pragma unroll
        for (int j = 0; j < 4; ++j)
            bfr[s][j] = *(const bf8_t*)(wbase + (c0 + 16 * j + rl) * 256 + s * 64 + kh * 16);

    // ---- stage A (f32 or packed-bf16 input; optional BN-affine+relu) ----
    {
        int kbase = (t & 7) * 16;
        float scv[16], shv[16];
        if (AFF) {
#pragma unroll
            for (int q = 0; q < 4; ++q) {
                float4 a4 = *(const float4*)&sc[kbase + q * 4];
                float4 b4 = *(const float4*)&sh[kbase + q * 4];
                scv[q*4+0]=a4.x; scv[q*4+1]=a4.y; scv[q*4+2]=a4.z; scv[q*4+3]=a4.w;
                shv[q*4+0]=b4.x; shv[q*4+1]=b4.y; shv[q*4+2]=b4.z; shv[q*4+3]=b4.w;
            }
        }
#pragma unroll
        for (int p = 0; p < 2; ++p) {
            int row = p * 32 + (t >> 3);
            int ar = brow + row; if (ar >= M) ar = M - 1;
            unsigned short vb[16];
            if (BF16IN) {
                const unsigned* src = (const unsigned*)Ain + (size_t)ar * 64 + (kbase >> 1);
                int4 r0 = *(const int4*)src;
                int4 r1 = *(const int4*)(src + 4);
                unsigned ua[8] = {(unsigned)r0.x,(unsigned)r0.y,(unsigned)r0.z,(unsigned)r0.w,
                                  (unsigned)r1.x,(unsigned)r1.y,(unsigned)r1.z,(unsigned)r1.w};
#pragma unroll
                for (int m = 0; m < 8; ++m) {
                    float f0 = __uint_as_float(ua[m] << 16);
                    float f1 = __uint_as_float(ua[m] & 0xFFFF0000u);
                    if (AFF) {
                        f0 = fmaxf(fmaf(f0, scv[2*m], shv[2*m]), 0.f);
                        f1 = fmaxf(fmaf(f1, scv[2*m+1], shv[2*m+1]), 0.f);
                    }
                    vb[2*m] = f2b(f0); vb[2*m+1] = f2b(f1);
                }
            } else {
                const float* src = (const float*)Ain + (size_t)ar * 128 + kbase;
#pragma unroll
                for (int q = 0; q < 4; ++q) {
                    float4 x4 = *(const float4*)&src[q * 4];
                    float vv[4] = {x4.x, x4.y, x4.z, x4.w};
#pragma unroll
                    for (int e = 0; e < 4; ++e) {
                        float f = vv[e];
                        if (AFF) f = fmaxf(fmaf(f, scv[q*4+e], shv[q*4+e]), 0.f);
                        vb[q * 4 + e] = f2b(f);
                    }
                }
            }
            int swz = (row & 7) << 4;
#pragma unroll
            for (int u = 0; u < 2; ++u) {
                int off = (row * 256 + kbase * 2 + u * 16) ^ swz;
                *(int4*)((char*)As + off) = *(int4*)&vb[u * 8];
            }
        }
    }
    __syncthreads();

    // ---- compute ----
    int swz = (rl & 7) << 4;
    f4_t acc[4][4];
#pragma unroll
    for (int i = 0; i < 4; ++i)
#pragma unroll
        for (int j = 0; j < 4; ++j) { f4_t z = {0.f,0.f,0.f,0.f}; acc[i][j] = z; }

    const char* Asc = (const char*)As;
#pragma unroll
    for (int s = 0; s < 4; ++s) {
        int kb2 = (s * 32 + kh * 8) * 2;
        bf8_t af[4];
#pragma unroll
        for (int i = 0; i < 4; ++i) {
            int row = 16 * i + rl;
            af[i] = *(const bf8_t*)(Asc + ((row * 256 + kb2) ^ swz));
        }
#pragma unroll
        for (int i = 0; i < 4; ++i)
#pragma unroll
            for (int j = 0; j < 4; ++j)
                acc[i][j] = __builtin_amdgcn_mfma_f32_16x16x32_bf16(af[i], bfr[s][j], acc[i][j], 0, 0, 0);
    }

    // ---- epilogue ----
    __syncthreads();
    short* Cs = (short*)lds;   // [64][256] bf16, swizzled (32 KB)
    const float* bb = mat ? br : bl;
    float blv[4];
#pragma unroll
    for (int j = 0; j < 4; ++j) blv[j] = bb[c0 + 16 * j + rl];

    // fused Al (source-logit) for xl waves: per-head 32-ch dot via rsum16.
    if (mat == 0) {
        const float sAl = 0.6f * LOG2E;
        float ap0 = att[c0 + rl] * sAl;
        float ap1 = att[c0 + 16 + rl] * sAl;
        float ap2 = att[c0 + 32 + rl] * sAl;
        float ap3 = att[c0 + 48 + rl] * sAl;
        float cl = fmaf(ap0, blv[0], ap1 * blv[1]);
        float ch = fmaf(ap2, blv[2], ap3 * blv[3]);
        int hbase = c0 >> 5;   // 0 (w=0) or 2 (w=1)
#pragma unroll
        for (int i = 0; i < 4; ++i)
#pragma unroll
            for (int q = 0; q < 4; ++q) {
                float pl = fmaf(ap0, acc[i][0][q], fmaf(ap1, acc[i][1][q], cl));
                float ph = fmaf(ap2, acc[i][2][q], fmaf(ap3, acc[i][3][q], ch));
                pl = rsum16(pl);
                ph = rsum16(ph);
                int node = brow + 16 * i + kh * 4 + q;
                if (rl == 0 && node < M) {
                    float2 w2 = make_float2(pl, ph);
                    *(float2*)&Al[(size_t)node * 4 + hbase] = w2;
                }
            }
    }

#pragma unroll
    for (int i = 0; i < 4; ++i)
#pragma unroll
        for (int j = 0; j < 4; ++j) {
            int col = mat * 128 + c0 + 16 * j + rl;
#pragma unroll
            for (int q = 0; q < 4; ++q) {
                int row = 16 * i + kh * 4 + q;
                int off = (row * 512 + col * 2) ^ ((row & 7) << 4);
                *(short*)((char*)Cs + off) = (short)f2b(acc[i][j][q] + blv[j]);
            }
        }
    __syncthreads();
#pragma unroll
    for (int rep = 0; rep < 8; ++rep) {
        int unit = rep * 256 + t;
        int row = unit >> 5;
        int slot = unit & 31;
        int gr = brow + row;
        if (gr < M) {
            int off = (row * 512 + slot * 16) ^ ((row & 7) << 4);
            int4 vv = *(const int4*)((char*)Cs + off);
            unsigned short* O = (slot < 16) ? xl : xr;
            int gcol = (slot & 15) * 8;
            *(int4*)&O[(size_t)gr * 128 + gcol] = vv;
        }
    }
}

// ===== fused edge softmax + aggregation + BN stats (round-12 epilogue:
// SP atomics then EXIT — no barrier after, no completion handshake) ==========
__global__ __launch_bounds__(256) void k_agg(
    const unsigned* __restrict__ xl, const unsigned* __restrict__ xr,
    const int* __restrict__ startA, const int* __restrict__ cntA,
    const unsigned* __restrict__ colB,
    const float* __restrict__ att, const float* __restrict__ bias,
    const float* __restrict__ Al, unsigned* __restrict__ hout,
    float* __restrict__ SP)
{
    int tid = threadIdx.x;
    int lane = tid & 63;
    int wv = tid >> 6;
    int n = blockIdx.x * 4 + wv;
    int e = lane >> 4;                 // edge slot 0..3
    int hq = lane & 15;                // h*4+q
    int h4 = (hq >> 2) * 4;            // byte offset of head in Al row
    unsigned hq16 = (unsigned)hq * 16u;
    const char* xlb = (const char*)xl;
    const char* alb = (const char*)Al;

    // att' slice (8 ch of this head-quarter), pre-scaled by 0.4*log2e
    float ap[8];
    {
        float4 q0 = *(const float4*)&att[hq * 8];
        float4 q1 = *(const float4*)&att[hq * 8 + 4];
        const float s = 0.4f * LOG2E;
        ap[0]=q0.x*s; ap[1]=q0.y*s; ap[2]=q0.z*s; ap[3]=q0.w*s;
        ap[4]=q1.x*s; ap[5]=q1.y*s; ap[6]=q1.z*s; ap[7]=q1.w*s;
    }
    // xr slice for this node
    float zx[8];
    {
        int4 xru = *(const int4*)((const char*)xr + (size_t)n * 256 + hq16);
        unpack8(xru, zx);
    }
    // Snode = 0.6*log2e * att_h . xr[n]  (= 1.5 * quadsum(dot(ap, zx)))
    float arp = ap[0] * zx[0];
#pragma unroll
    for (int c = 1; c < 8; ++c) arp = fmaf(ap[c], zx[c], arp);
    float Snode = 1.5f * quadsum(arp);

    int a0i = startA[n];
    int cn = cntA[n];                  // >= 1 (self loop)
    int nb = (cn + 3) >> 2;

    // pipeline prologue (bucket tail pads zeroed -> stray reads hit node 0,
    // masked out by wg)
    unsigned off0 = colB[a0i + e];
    float al0 = *(const float*)(alb + ((off0 >> 4) & ~15u) + h4);
    int4 d0 = *(const int4*)(xlb + off0 + hq16);
    unsigned off1 = off0;
    if (nb > 1) off1 = colB[a0i + 4 + e];

    float acc[8] = {0.f,0.f,0.f,0.f,0.f,0.f,0.f,0.f};
    float wsum = 0.f;

    for (int b = 0; b < nb; ++b) {
        unsigned off2 = off1;
        if (b + 2 < nb) off2 = colB[a0i + (b + 2) * 4 + e];
        float al1 = al0; int4 d1 = d0;
        if (b + 1 < nb) {
            al1 = *(const float*)(alb + ((off1 >> 4) & ~15u) + h4);
            d1 = *(const int4*)(xlb + off1 + hq16);
        }
        float z[8]; unpack8(d0, z);
        float t0 = z[0] + zx[0];
        float D = ap[0] * fabsf(t0);
#pragma unroll
        for (int c = 1; c < 8; ++c) {
            float tc = z[c] + zx[c];
            D = fmaf(ap[c], fabsf(tc), D);
        }
        D = quadsum(D);
        float wg = exp2f(al0 + Snode + D);
        if (b == nb - 1) wg = (b * 4 + e < cn) ? wg : 0.f;   // tail mask
#pragma unroll
        for (int c = 0; c < 8; ++c) acc[c] = fmaf(wg, z[c], acc[c]);
        wsum += wg;
        off0 = off1; off1 = off2; al0 = al1; d0 = d1;
    }

    // reduce across the 4 edge groups (lanes xor 16, 32)
#pragma unroll
    for (int c = 0; c < 8; ++c) {
        acc[c] += __shfl_xor(acc[c], 16, 64);
        acc[c] += __shfl_xor(acc[c], 32, 64);
    }
    wsum += __shfl_xor(wsum, 16, 64);
    wsum += __shfl_xor(wsum, 32, 64);

    float inv = 1.f / wsum;
    float4 b0 = *(const float4*)&bias[hq * 8];
    float4 b1 = *(const float4*)&bias[hq * 8 + 4];
    float bv[8] = {b0.x,b0.y,b0.z,b0.w,b1.x,b1.y,b1.z,b1.w};
    float ov[8];
    unsigned r[4];
#pragma unroll
    for (int k = 0; k < 4; ++k) {
        float o0 = fmaf(acc[2*k],     inv, bv[2*k]);
        float o1 = fmaf(acc[2*k + 1], inv, bv[2*k + 1]);
        ov[2*k] = o0; ov[2*k+1] = o1;
        r[k] = (unsigned)f2b(o0) | ((unsigned)f2b(o1) << 16);
    }

    // BN stats: per-node (lane<16 holds the 128 channels, 8 each)
    __shared__ float sO[4][128], sQ[4][128];
    if (lane < 16) {
        *(int4*)((char*)hout + (size_t)n * 256 + hq16) = *(int4*)r;
#pragma unroll
        for (int c = 0; c < 8; ++c) {
            sO[wv][hq * 8 + c] = ov[c];
            sQ[wv][hq * 8 + c] = ov[c] * ov[c];
        }
    }
    __syncthreads();
    if (tid < 128) {
        float s = sO[0][tid] + sO[1][tid] + sO[2][tid] + sO[3][tid];
        float q = sQ[0][tid] + sQ[1][tid] + sQ[2][tid] + sQ[3][tid];
        float* slot = SP + (size_t)(blockIdx.x & (NSLOT - 1)) * 256;
        atomicAdd(&slot[tid], s);
        atomicAdd(&slot[128 + tid], q);
    }
    // fire-and-exit: no trailing barrier, no completion handshake.
}

// ================= BN finalize: reduce 64 partials -> scsh, re-zero =========
__global__ void k_bnfinal(float* __restrict__ SP,
                          const float* __restrict__ g, const float* __restrict__ be,
                          float* __restrict__ sc, float* __restrict__ sh) {
    int c = threadIdx.x;   // 128
    float s = 0.f, q = 0.f;
    for (int j = 0; j < NSLOT; ++j) {
        s += SP[j * 256 + c];
        q += SP[j * 256 + 128 + c];
    }
    float mu = s * (1.f / N_NODES);
    float var = q * (1.f / N_NODES) - mu * mu;
    float sv = rsqrtf(var + EPS_BN) * g[c];
    sc[c] = sv;
    sh[c] = be[c] - mu * sv;
    for (int j = 0; j < NSLOT; ++j) {     // re-zero for the next layer/replay
        SP[j * 256 + c] = 0.f;
        SP[j * 256 + 128 + c] = 0.f;
    }
}

// ====== tail: per-graph mean pool (BN2 affine+relu fused) + MLP head ========
__global__ __launch_bounds__(256) void k_tail(
    const unsigned* __restrict__ h, const int* __restrict__ gstart,
    const float* __restrict__ gf,
    const float* __restrict__ sc, const float* __restrict__ sh,
    const float* __restrict__ W1, const float* __restrict__ b1,
    const float* __restrict__ W2, const float* __restrict__ b2,
    float* __restrict__ out)
{
    int g = blockIdx.x;
    int t = threadIdx.x;
    int wv = t >> 6;
    int lane = t & 63;
    int c0 = lane * 2;

    float sc0 = sc[c0], sc1 = sc[c0 + 1], sh0 = sh[c0], sh1 = sh[c0 + 1];
    int r0 = gstart[g], r1 = gstart[g + 1];
    float s0 = 0.f, s1 = 0.f;
    for (int r = r0 + wv; r < r1; r += 4) {
        unsigned u = h[(size_t)r * 64 + lane];
        float v0 = __uint_as_float(u << 16);
        float v1 = __uint_as_float(u & 0xFFFF0000u);
        s0 += fmaxf(fmaf(v0, sc0, sh0), 0.f);
        s1 += fmaxf(fmaf(v1, sc1, sh1), 0.f);
    }
    __shared__ float sP[4][128];
    sP[wv][c0] = s0;
    sP[wv][c0 + 1] = s1;
    __syncthreads();

    __shared__ float zs[160];
    __shared__ float red[4];
    float invc = 1.f / fmaxf((float)(r1 - r0), 1.f);
    if (t < 128)
        zs[t] = (sP[0][t] + sP[1][t] + sP[2][t] + sP[3][t]) * invc;
    else if (t < 160)
        zs[t] = gf[(size_t)g * 32 + (t - 128)];
    __syncthreads();

    float acc = b1[t];
#pragma unroll 8
    for (int i = 0; i < 160; i++) acc = fmaf(zs[i], W1[i * 256 + t], acc);
    acc = fmaxf(acc, 0.f);
    float part = acc * W2[t];
    part += __shfl_xor(part, 32, 64);
    part += __shfl_xor(part, 16, 64);
    part += __shfl_xor(part, 8, 64);
    part += __shfl_xor(part, 4, 64);
    part += __shfl_xor(part, 2, 64);
    part += __shfl_xor(part, 1, 64);
    if ((t & 63) == 0) red[t >> 6] = part;
    __syncthreads();
    if (t == 0) out[g] = red[0] + red[1] + red[2] + red[3] + b2[0];
}

extern "C" void kernel_launch(void* const* d_in, const int* in_sizes, int n_in,
                              void* d_out, int out_size, void* d_ws, size_t ws_size,
                              hipStream_t stream) {
    (void)in_sizes; (void)n_in; (void)out_size; (void)ws_size;

    const float* x     = (const float*)d_in[0];
    const int*   ei    = (const int*)d_in[1];
    const int*   batch = (const int*)d_in[2];
    const float* gf    = (const float*)d_in[3];
    const float* Wl1 = (const float*)d_in[4];
    const float* bl1 = (const float*)d_in[5];
    const float* Wr1 = (const float*)d_in[6];
    const float* br1 = (const float*)d_in[7];
    const float* att1  = (const float*)d_in[8];
    const float* bias1 = (const float*)d_in[9];
    const float* g1  = (const float*)d_in[10];
    const float* be1 = (const float*)d_in[11];
    const float* Wl2 = (const float*)d_in[12];
    const float* bl2 = (const float*)d_in[13];
    const float* Wr2 = (const float*)d_in[14];
    const float* br2 = (const float*)d_in[15];
    const float* att2  = (const float*)d_in[16];
    const float* bias2 = (const float*)d_in[17];
    const float* g2  = (const float*)d_in[18];
    const float* be2 = (const float*)d_in[19];
    const float* Wfc1 = (const float*)d_in[20];
    const float* bfc1 = (const float*)d_in[21];
    const float* Wfc2 = (const float*)d_in[22];
    const float* bfc2 = (const float*)d_in[23];
    float* out = (float*)d_out;

    char* ws = (char*)d_ws;
    unsigned short* xl = (unsigned short*)(ws + 0);            // 25.6 MB bf16
    unsigned short* xr = (unsigned short*)(ws + 25600000);     // 25.6 MB bf16
    unsigned* h     = (unsigned*)(ws + 51200000);              // 25.6 MB bf16 packed
    int*   colA     = (int*)(ws + 76800000);                   // 9.63 MB (bucketed)
    int*   bktBuf   = (int*)(ws + 86434560);                   // 9.63 MB packed ints
    int*   bucketCur= (int*)(ws + 96068608);                   // 1 KB
    float* SP       = (float*)(ws + 96069632);                 // 64 KB (64 slots)
    int*   cntA     = (int*)(ws + 96135168);                   // 400 KB
    int*   startA   = (int*)(ws + 96535168);                   // 400 KB
    float* scsh     = (float*)(ws + 96935168);                 // 2 KB: sc1|sh1|sc2|sh2
    int*   gstart   = (int*)(ws + 96937216);                   // 4.1 KB
    unsigned short* Wimg1 = (unsigned short*)(ws + 96941568);  // 64 KB
    unsigned short* Wimg2 = (unsigned short*)(ws + 97007104);  // 64 KB
    float* Al       = (float*)(ws + 97072640);                 // 1.6 MB [N][4]

    // prep (W images, graph bounds, zero bucketCur/SP) + CSR build
    k_prep<<<425, 256, 0, stream>>>(Wl1, Wr1, Wl2, Wr2, Wimg1, Wimg2,
                                    batch, gstart, bucketCur, SP);
    k_part<<<(EP + 4095) / 4096, 256, 0, stream>>>(ei, bucketCur, bktBuf);
    k_build<<<NB, 512, 0, stream>>>(bktBuf, bucketCur, startA, cntA, colA);

    int gemm_grid = (N_NODES + 63) / 64;

    // Layer 1
    k_gemm<false, false><<<gemm_grid, 256, 0, stream>>>(x, Wimg1, bl1, br1,
                                                        nullptr, nullptr, att1, Al,
                                                        xl, xr, N_NODES);
    k_agg<<<N_NODES / 4, 256, 0, stream>>>((const unsigned*)xl, (const unsigned*)xr,
                                           startA, cntA, (const unsigned*)colA,
                                           att1, bias1, Al, h, SP);
    k_bnfinal<<<1, 128, 0, stream>>>(SP, g1, be1, scsh + 0, scsh + 128);

    // Layer 2 (BN1 apply + ReLU fused into GEMM A-staging, bf16 input)
    k_gemm<true, true><<<gemm_grid, 256, 0, stream>>>(h, Wimg2, bl2, br2,
                                                      scsh + 0, scsh + 128, att2, Al,
                                                      xl, xr, N_NODES);
    k_agg<<<N_NODES / 4, 256, 0, stream>>>((const unsigned*)xl, (const unsigned*)xr,
                                           startA, cntA, (const unsigned*)colA,
                                           att2, bias2, Al, h, SP);
    k_bnfinal<<<1, 128, 0, stream>>>(SP, g2, be2, scsh + 256, scsh + 384);

    // Tail: pool (BN2 affine+relu fused) + MLP, one launch
    k_tail<<<NG, 256, 0, stream>>>(h, gstart, gf, scsh + 256, scsh + 384,
                                   Wfc1, bfc1, Wfc2, bfc2, out);
}

// Round 16
// 299.244 us; speedup vs baseline: 6.1227x; 1.0413x over previous
//
#include <hip/hip_runtime.h>
#include <hip/hip_bf16.h>

#define N_NODES 100000
#define E_EDGES 1600000
#define EP (E_EDGES + N_NODES)
#define NG 1024
#define NEG 0.2f
#define EPS_BN 1e-5f
#define LOG2E 1.44269504088896f

#define NB 196        // dst buckets of 512 nodes
#define BCAP 12288    // per-bucket capacity (mean 8704)
#define NSLOT 64      // BN partial slots (64 -> low same-address contention)

typedef __attribute__((ext_vector_type(8))) short bf8_t;
typedef __attribute__((ext_vector_type(4))) float f4_t;

// pack 2 f32 -> 2 bf16 (RNE) in one u32; compiles to v_cvt_pk_bf16_f32 (T12:
// use the HIP cast and let the compiler emit/schedule it — never inline-asm).
__device__ __forceinline__ unsigned pk2(float lo, float hi) {
    __hip_bfloat162 b = __float22bfloat162_rn(make_float2(lo, hi));
    union { __hip_bfloat162 b; unsigned u; } c;
    c.b = b;
    return c.u;
}

// 16-lane sum via mov_dpp row_ror butterfly; result broadcast to 16 lanes.
__device__ __forceinline__ float rsum16(float p) {
    p += __int_as_float(__builtin_amdgcn_mov_dpp(__float_as_int(p), 0x128, 0xf, 0xf, true));
    p += __int_as_float(__builtin_amdgcn_mov_dpp(__float_as_int(p), 0x124, 0xf, 0xf, true));
    p += __int_as_float(__builtin_amdgcn_mov_dpp(__float_as_int(p), 0x122, 0xf, 0xf, true));
    p += __int_as_float(__builtin_amdgcn_mov_dpp(__float_as_int(p), 0x121, 0xf, 0xf, true));
    return p;
}

// 4-lane (quad) sum via quad_perm DPP; result broadcast to all 4 lanes.
__device__ __forceinline__ float quadsum(float p) {
    p += __int_as_float(__builtin_amdgcn_mov_dpp(__float_as_int(p), 0xB1, 0xf, 0xf, true)); // [1,0,3,2]
    p += __int_as_float(__builtin_amdgcn_mov_dpp(__float_as_int(p), 0x4E, 0xf, 0xf, true)); // [2,3,0,1]
    return p;
}

__device__ __forceinline__ void unpack8(const int4& d, float* z) {
    unsigned a = (unsigned)d.x, b = (unsigned)d.y, c = (unsigned)d.z, w = (unsigned)d.w;
    z[0] = __uint_as_float(a << 16); z[1] = __uint_as_float(a & 0xFFFF0000u);
    z[2] = __uint_as_float(b << 16); z[3] = __uint_as_float(b & 0xFFFF0000u);
    z[4] = __uint_as_float(c << 16); z[5] = __uint_as_float(c & 0xFFFF0000u);
    z[6] = __uint_as_float(w << 16); z[7] = __uint_as_float(w & 0xFFFF0000u);
}

// ================= CSR build: partition -> per-bucket build (packed int) =====
// buf entry = (src << 9) | (dst & 511); bucket = dst >> 9.
__global__ __launch_bounds__(256) void k_part(const int* __restrict__ ei,
                                              int* __restrict__ bucketCur,
                                              int* __restrict__ buf) {
    __shared__ int lh[NB], lb[NB];
    int t = threadIdx.x;
    for (int i = t; i < NB; i += 256) lh[i] = 0;
    __syncthreads();
    int base = blockIdx.x * 4096;
    int pk[16];
    int bk[16];
    int rk[16];
#pragma unroll
    for (int i = 0; i < 16; i++) {
        int idx = base + i * 256 + t;
        int s, d;
        if (idx < E_EDGES) { s = ei[idx]; d = ei[E_EDGES + idx]; }
        else if (idx < EP) { s = d = idx - E_EDGES; }
        else { s = 0; d = -1; }
        pk[i] = (s << 9) | (d & 511);
        bk[i] = d >> 9;
        rk[i] = (d >= 0) ? atomicAdd(&lh[d >> 9], 1) : 0;
    }
    __syncthreads();
    for (int i = t; i < NB; i += 256) lb[i] = atomicAdd(&bucketCur[i], lh[i]);
    __syncthreads();
#pragma unroll
    for (int i = 0; i < 16; i++) {
        int bkt = bk[i];
        if (bkt >= 0)
            buf[(size_t)bkt * BCAP + lb[bkt] + rk[i]] = pk[i];
    }
}

// per-bucket: histogram -> LDS scan -> startA/cntA -> place colA (byte offsets)
// + zero a 16-int tail pad after each bucket's used region (pipeline over-reads)
__global__ __launch_bounds__(512) void k_build(const int* __restrict__ buf,
                                               const int* __restrict__ bcnt,
                                               int* __restrict__ startA,
                                               int* __restrict__ cntA,
                                               int* __restrict__ colA) {
    __shared__ int h[512];
    __shared__ int s[512];
    int b = blockIdx.x, t = threadIdx.x;
    h[t] = 0;
    __syncthreads();
    int n = bcnt[b];
    const int* p = buf + (size_t)b * BCAP;
    for (int i = t; i < n; i += 512) atomicAdd(&h[p[i] & 511], 1);
    __syncthreads();
    int v = h[t];
    s[t] = v;
    __syncthreads();
    for (int o = 1; o < 512; o <<= 1) {
        int u = (t >= o) ? s[t - o] : 0;
        __syncthreads();
        s[t] += u;
        __syncthreads();
    }
    int myStart = b * BCAP + s[t] - v;   // exclusive prefix within bucket
    int node = (b << 9) + t;
    if (node < N_NODES) {
        startA[node] = myStart;
        cntA[node] = v;
    }
    h[t] = myStart;                      // reuse as running cursor
    __syncthreads();
    for (int i = t; i < n; i += 512) {
        int e = p[i];
        int r = atomicAdd(&h[e & 511], 1);
        colA[r] = (e >> 9) << 8;         // src * 256 (byte offset into xl)
    }
    if (t < 16) colA[b * BCAP + n + t] = 0;   // tail pad (stray reads -> node 0)
}

// === prep: wconv L1+L2 (blocks 0..31) + gstart (32..422) + zero (423..424) ===
__global__ __launch_bounds__(256) void k_prep(
    const float* __restrict__ Wl1, const float* __restrict__ Wr1,
    const float* __restrict__ Wl2, const float* __restrict__ Wr2,
    unsigned short* __restrict__ img1, unsigned short* __restrict__ img2,
    const int* __restrict__ batch, int* __restrict__ gstart,
    int* __restrict__ bucketCur, float* __restrict__ SP) {
    int blk = blockIdx.x;
    int t = threadIdx.x;
    if (blk < 32) {
        int lay = blk >> 4;
        int g = (blk & 15) * 256 + t;   // 4096 chunks per layer
        int m = g >> 11, n = (g >> 4) & 127, kb = g & 15;
        const float* W = lay ? (m ? Wr2 : Wl2) : (m ? Wr1 : Wl1);
        unsigned short* img = lay ? img2 : img1;
        unsigned vw[4];
#pragma unroll
        for (int j = 0; j < 4; j++)
            vw[j] = pk2(W[(kb * 8 + 2 * j) * 128 + n],
                        W[(kb * 8 + 2 * j + 1) * 128 + n]);
        int off = m * 32768 + n * 256 + kb * 16;
        *(int4*)((char*)img + off) = *(int4*)vw;
    } else if (blk < 423) {
        int i = (blk - 32) * 256 + t;
        if (i >= N_NODES) return;
        int b = batch[i];
        int prev = (i == 0) ? -1 : batch[i - 1];
        for (int g = prev + 1; g <= b; g++) gstart[g] = i;
        if (i == N_NODES - 1)
            for (int g = b + 1; g <= NG; g++) gstart[g] = N_NODES;
    } else if (blk == 423) {
        if (t < NB) bucketCur[t] = 0;
    } else {
        // zero SP: NSLOT*256 floats = 16384 floats = 64 KB
        float4 zz = {0.f, 0.f, 0.f, 0.f};
#pragma unroll
        for (int j = 0; j < 16; ++j)
            *(float4*)&SP[(j * 256 + t) * 4] = zz;
    }
}

// ================= MFMA dual GEMM: xl = A@Wl + bl, xr = A@Wr + br (bf16) =====
// W fragments straight from global (L2-hot). Fused epilogue also emits
// Al[n][h] = 0.6*log2e * att_h . xl[n]  (from f32 accumulators, mat=0 waves).
template<bool AFF, bool BF16IN>
__global__ __launch_bounds__(256) void k_gemm(
    const void* __restrict__ Ain, const unsigned short* __restrict__ Wimg,
    const float* __restrict__ bl, const float* __restrict__ br,
    const float* __restrict__ sc, const float* __restrict__ sh,
    const float* __restrict__ att, float* __restrict__ Al,
    unsigned short* __restrict__ xl, unsigned short* __restrict__ xr, int M)
{
    __shared__ char lds[32768];
    short* As = (short*)lds;             // 16384 B

    int t = threadIdx.x;
    int lane = t & 63;
    int w = t >> 6;
    int brow = blockIdx.x * 64;

    int rl = lane & 15;
    int kh = lane >> 4;
    int mat = w >> 1;
    int c0 = (w & 1) * 64;

    // ---- B fragments from global (issued first, overlap with A staging) ----
    const char* wbase = (const char*)Wimg + mat * 32768;
    bf8_t bfr[4][4];
#pragma unroll
    for (int s = 0; s < 4; ++s)
#pragma unroll
        for (int j = 0; j < 4; ++j)
            bfr[s][j] = *(const bf8_t*)(wbase + (c0 + 16 * j + rl) * 256 + s * 64 + kh * 16);

    // ---- stage A (f32 or packed-bf16 input; optional BN-affine+relu) ----
    {
        int kbase = (t & 7) * 16;
        float scv[16], shv[16];
        if (AFF) {
#pragma unroll
            for (int q = 0; q < 4; ++q) {
                float4 a4 = *(const float4*)&sc[kbase + q * 4];
                float4 b4 = *(const float4*)&sh[kbase + q * 4];
                scv[q*4+0]=a4.x; scv[q*4+1]=a4.y; scv[q*4+2]=a4.z; scv[q*4+3]=a4.w;
                shv[q*4+0]=b4.x; shv[q*4+1]=b4.y; shv[q*4+2]=b4.z; shv[q*4+3]=b4.w;
            }
        }
#pragma unroll
        for (int p = 0; p < 2; ++p) {
            int row = p * 32 + (t >> 3);
            int ar = brow + row; if (ar >= M) ar = M - 1;
            unsigned vb32[8];
            if (BF16IN) {
                const unsigned* src = (const unsigned*)Ain + (size_t)ar * 64 + (kbase >> 1);
                int4 r0 = *(const int4*)src;
                int4 r1 = *(const int4*)(src + 4);
                unsigned ua[8] = {(unsigned)r0.x,(unsigned)r0.y,(unsigned)r0.z,(unsigned)r0.w,
                                  (unsigned)r1.x,(unsigned)r1.y,(unsigned)r1.z,(unsigned)r1.w};
#pragma unroll
                for (int m = 0; m < 8; ++m) {
                    float f0 = __uint_as_float(ua[m] << 16);
                    float f1 = __uint_as_float(ua[m] & 0xFFFF0000u);
                    if (AFF) {
                        f0 = fmaxf(fmaf(f0, scv[2*m], shv[2*m]), 0.f);
                        f1 = fmaxf(fmaf(f1, scv[2*m+1], shv[2*m+1]), 0.f);
                        vb32[m] = pk2(f0, f1);
                    } else {
                        vb32[m] = ua[m];   // passthrough, already bf16 pair
                    }
                }
            } else {
                const float* src = (const float*)Ain + (size_t)ar * 128 + kbase;
#pragma unroll
                for (int q = 0; q < 4; ++q) {
                    float4 x4 = *(const float4*)&src[q * 4];
                    float vv[4] = {x4.x, x4.y, x4.z, x4.w};
                    if (AFF) {
#pragma unroll
                        for (int e = 0; e < 4; ++e)
                            vv[e] = fmaxf(fmaf(vv[e], scv[q*4+e], shv[q*4+e]), 0.f);
                    }
                    vb32[q * 2]     = pk2(vv[0], vv[1]);
                    vb32[q * 2 + 1] = pk2(vv[2], vv[3]);
                }
            }
            int swz = (row & 7) << 4;
#pragma unroll
            for (int u = 0; u < 2; ++u) {
                int off = (row * 256 + kbase * 2 + u * 16) ^ swz;
                *(int4*)((char*)As + off) = *(int4*)&vb32[u * 4];
            }
        }
    }
    __syncthreads();

    // ---- compute ----
    int swz = (rl & 7) << 4;
    f4_t acc[4][4];
#pragma unroll
    for (int i = 0; i < 4; ++i)
#pragma unroll
        for (int j = 0; j < 4; ++j) { f4_t z = {0.f,0.f,0.f,0.f}; acc[i][j] = z; }

    const char* Asc = (const char*)As;
#pragma unroll
    for (int s = 0; s < 4; ++s) {
        int kb2 = (s * 32 + kh * 8) * 2;
        bf8_t af[4];
#pragma unroll
        for (int i = 0; i < 4; ++i) {
            int row = 16 * i + rl;
            af[i] = *(const bf8_t*)(Asc + ((row * 256 + kb2) ^ swz));
        }
#pragma unroll
        for (int i = 0; i < 4; ++i)
#pragma unroll
            for (int j = 0; j < 4; ++j)
                acc[i][j] = __builtin_amdgcn_mfma_f32_16x16x32_bf16(af[i], bfr[s][j], acc[i][j], 0, 0, 0);
    }

    // ---- epilogue ----
    __syncthreads();
    short* Cs = (short*)lds;   // [64][256] bf16, swizzled (32 KB)
    const float* bb = mat ? br : bl;
    float blv[4];
#pragma unroll
    for (int j = 0; j < 4; ++j) blv[j] = bb[c0 + 16 * j + rl];

    // fused Al (source-logit) for xl waves: per-head 32-ch dot via rsum16.
    if (mat == 0) {
        const float sAl = 0.6f * LOG2E;
        float ap0 = att[c0 + rl] * sAl;
        float ap1 = att[c0 + 16 + rl] * sAl;
        float ap2 = att[c0 + 32 + rl] * sAl;
        float ap3 = att[c0 + 48 + rl] * sAl;
        float cl = fmaf(ap0, blv[0], ap1 * blv[1]);
        float ch = fmaf(ap2, blv[2], ap3 * blv[3]);
        int hbase = c0 >> 5;   // 0 (w=0) or 2 (w=1)
#pragma unroll
        for (int i = 0; i < 4; ++i)
#pragma unroll
            for (int q = 0; q < 4; ++q) {
                float pl = fmaf(ap0, acc[i][0][q], fmaf(ap1, acc[i][1][q], cl));
                float ph = fmaf(ap2, acc[i][2][q], fmaf(ap3, acc[i][3][q], ch));
                pl = rsum16(pl);
                ph = rsum16(ph);
                int node = brow + 16 * i + kh * 4 + q;
                if (rl == 0 && node < M) {
                    float2 w2 = make_float2(pl, ph);
                    *(float2*)&Al[(size_t)node * 4 + hbase] = w2;
                }
            }
    }

#pragma unroll
    for (int i = 0; i < 4; ++i)
#pragma unroll
        for (int j = 0; j < 4; ++j) {
            int col = mat * 128 + c0 + 16 * j + rl;
            unsigned u01 = pk2(acc[i][j][0] + blv[j], acc[i][j][1] + blv[j]);
            unsigned u23 = pk2(acc[i][j][2] + blv[j], acc[i][j][3] + blv[j]);
            unsigned short vq[4] = {(unsigned short)u01, (unsigned short)(u01 >> 16),
                                    (unsigned short)u23, (unsigned short)(u23 >> 16)};
#pragma unroll
            for (int q = 0; q < 4; ++q) {
                int row = 16 * i + kh * 4 + q;
                int off = (row * 512 + col * 2) ^ ((row & 7) << 4);
                *(unsigned short*)((char*)Cs + off) = vq[q];
            }
        }
    __syncthreads();
#pragma unroll
    for (int rep = 0; rep < 8; ++rep) {
        int unit = rep * 256 + t;
        int row = unit >> 5;
        int slot = unit & 31;
        int gr = brow + row;
        if (gr < M) {
            int off = (row * 512 + slot * 16) ^ ((row & 7) << 4);
            int4 vv = *(const int4*)((char*)Cs + off);
            unsigned short* O = (slot < 16) ? xl : xr;
            int gcol = (slot & 15) * 8;
            *(int4*)&O[(size_t)gr * 128 + gcol] = vv;
        }
    }
}

// ===== fused edge softmax + aggregation + BN stats (fire-and-exit epilogue) ==
__global__ __launch_bounds__(256) void k_agg(
    const unsigned* __restrict__ xl, const unsigned* __restrict__ xr,
    const int* __restrict__ startA, const int* __restrict__ cntA,
    const unsigned* __restrict__ colB,
    const float* __restrict__ att, const float* __restrict__ bias,
    const float* __restrict__ Al, unsigned* __restrict__ hout,
    float* __restrict__ SP)
{
    int tid = threadIdx.x;
    int lane = tid & 63;
    int wv = tid >> 6;
    int n = blockIdx.x * 4 + wv;
    int e = lane >> 4;                 // edge slot 0..3
    int hq = lane & 15;                // h*4+q
    int h4 = (hq >> 2) * 4;            // byte offset of head in Al row
    unsigned hq16 = (unsigned)hq * 16u;
    const char* xlb = (const char*)xl;
    const char* alb = (const char*)Al;

    // att' slice (8 ch of this head-quarter), pre-scaled by 0.4*log2e
    float ap[8];
    {
        float4 q0 = *(const float4*)&att[hq * 8];
        float4 q1 = *(const float4*)&att[hq * 8 + 4];
        const float s = 0.4f * LOG2E;
        ap[0]=q0.x*s; ap[1]=q0.y*s; ap[2]=q0.z*s; ap[3]=q0.w*s;
        ap[4]=q1.x*s; ap[5]=q1.y*s; ap[6]=q1.z*s; ap[7]=q1.w*s;
    }
    // xr slice for this node
    float zx[8];
    {
        int4 xru = *(const int4*)((const char*)xr + (size_t)n * 256 + hq16);
        unpack8(xru, zx);
    }
    // Snode = 0.6*log2e * att_h . xr[n]  (= 1.5 * quadsum(dot(ap, zx)))
    float arp = ap[0] * zx[0];
#pragma unroll
    for (int c = 1; c < 8; ++c) arp = fmaf(ap[c], zx[c], arp);
    float Snode = 1.5f * quadsum(arp);

    int a0i = startA[n];
    int cn = cntA[n];                  // >= 1 (self loop)
    int nb = (cn + 3) >> 2;

    // pipeline prologue (bucket tail pads zeroed -> stray reads hit node 0,
    // masked out by wg)
    unsigned off0 = colB[a0i + e];
    float al0 = *(const float*)(alb + ((off0 >> 4) & ~15u) + h4);
    int4 d0 = *(const int4*)(xlb + off0 + hq16);
    unsigned off1 = off0;
    if (nb > 1) off1 = colB[a0i + 4 + e];

    float acc[8] = {0.f,0.f,0.f,0.f,0.f,0.f,0.f,0.f};
    float wsum = 0.f;

    for (int b = 0; b < nb; ++b) {
        unsigned off2 = off1;
        if (b + 2 < nb) off2 = colB[a0i + (b + 2) * 4 + e];
        float al1 = al0; int4 d1 = d0;
        if (b + 1 < nb) {
            al1 = *(const float*)(alb + ((off1 >> 4) & ~15u) + h4);
            d1 = *(const int4*)(xlb + off1 + hq16);
        }
        float z[8]; unpack8(d0, z);
        float t0 = z[0] + zx[0];
        float D = ap[0] * fabsf(t0);
#pragma unroll
        for (int c = 1; c < 8; ++c) {
            float tc = z[c] + zx[c];
            D = fmaf(ap[c], fabsf(tc), D);
        }
        D = quadsum(D);
        float wg = exp2f(al0 + Snode + D);
        if (b == nb - 1) wg = (b * 4 + e < cn) ? wg : 0.f;   // tail mask
#pragma unroll
        for (int c = 0; c < 8; ++c) acc[c] = fmaf(wg, z[c], acc[c]);
        wsum += wg;
        off0 = off1; off1 = off2; al0 = al1; d0 = d1;
    }

    // reduce across the 4 edge groups (lanes xor 16, 32)
#pragma unroll
    for (int c = 0; c < 8; ++c) {
        acc[c] += __shfl_xor(acc[c], 16, 64);
        acc[c] += __shfl_xor(acc[c], 32, 64);
    }
    wsum += __shfl_xor(wsum, 16, 64);
    wsum += __shfl_xor(wsum, 32, 64);

    float inv = 1.f / wsum;
    float4 b0 = *(const float4*)&bias[hq * 8];
    float4 b1 = *(const float4*)&bias[hq * 8 + 4];
    float bv[8] = {b0.x,b0.y,b0.z,b0.w,b1.x,b1.y,b1.z,b1.w};
    float ov[8];
    unsigned r[4];
#pragma unroll
    for (int k = 0; k < 4; ++k) {
        float o0 = fmaf(acc[2*k],     inv, bv[2*k]);
        float o1 = fmaf(acc[2*k + 1], inv, bv[2*k + 1]);
        ov[2*k] = o0; ov[2*k+1] = o1;
        r[k] = pk2(o0, o1);
    }

    // BN stats: per-node (lane<16 holds the 128 channels, 8 each)
    __shared__ float sO[4][128], sQ[4][128];
    if (lane < 16) {
        *(int4*)((char*)hout + (size_t)n * 256 + hq16) = *(int4*)r;
#pragma unroll
        for (int c = 0; c < 8; ++c) {
            sO[wv][hq * 8 + c] = ov[c];
            sQ[wv][hq * 8 + c] = ov[c] * ov[c];
        }
    }
    __syncthreads();
    if (tid < 128) {
        float s = sO[0][tid] + sO[1][tid] + sO[2][tid] + sO[3][tid];
        float q = sQ[0][tid] + sQ[1][tid] + sQ[2][tid] + sQ[3][tid];
        float* slot = SP + (size_t)(blockIdx.x & (NSLOT - 1)) * 256;
        atomicAdd(&slot[tid], s);
        atomicAdd(&slot[128 + tid], q);
    }
    // fire-and-exit: no trailing barrier, no completion handshake.
}

// ================= BN finalize (L1): reduce partials -> scsh, re-zero =======
__global__ void k_bnfinal(float* __restrict__ SP,
                          const float* __restrict__ g, const float* __restrict__ be,
                          float* __restrict__ sc, float* __restrict__ sh) {
    int c = threadIdx.x;   // 128
    float s = 0.f, q = 0.f;
    for (int j = 0; j < NSLOT; ++j) {
        s += SP[j * 256 + c];
        q += SP[j * 256 + 128 + c];
    }
    float mu = s * (1.f / N_NODES);
    float var = q * (1.f / N_NODES) - mu * mu;
    float sv = rsqrtf(var + EPS_BN) * g[c];
    sc[c] = sv;
    sh[c] = be[c] - mu * sv;
    for (int j = 0; j < NSLOT; ++j) {     // re-zero for layer-2 accumulation
        SP[j * 256 + c] = 0.f;
        SP[j * 256 + 128 + c] = 0.f;
    }
}

// ====== tail: BN2 finalize (inline, per block) + mean pool + MLP head =======
// SP is left dirty after this call; k_prep re-zeros it at the start of the
// next call (graph-replay safe).
__global__ __launch_bounds__(256) void k_tail(
    const unsigned* __restrict__ h, const int* __restrict__ gstart,
    const float* __restrict__ gf, const float* __restrict__ SP,
    const float* __restrict__ gg, const float* __restrict__ be,
    const float* __restrict__ W1, const float* __restrict__ b1,
    const float* __restrict__ W2, const float* __restrict__ b2,
    float* __restrict__ out)
{
    int g = blockIdx.x;
    int t = threadIdx.x;
    int wv = t >> 6;
    int lane = t & 63;
    int c0 = lane * 2;

    // BN2 finalize, redundant per block (SP is L2-hot: 64 loads/thread)
    __shared__ float sSC[128], sSH[128], fin[256];
    {
        int c = t & 127, half = t >> 7;
        float v = 0.f;
#pragma unroll
        for (int j = 0; j < NSLOT; ++j) v += SP[j * 256 + half * 128 + c];
        fin[t] = v;
    }
    __syncthreads();
    if (t < 128) {
        float s = fin[t], q = fin[128 + t];
        float mu = s * (1.f / N_NODES);
        float var = q * (1.f / N_NODES) - mu * mu;
        float sv = rsqrtf(var + EPS_BN) * gg[t];
        sSC[t] = sv;
        sSH[t] = be[t] - mu * sv;
    }
    __syncthreads();

    float sc0 = sSC[c0], sc1 = sSC[c0 + 1], sh0 = sSH[c0], sh1 = sSH[c0 + 1];
    int r0 = gstart[g], r1 = gstart[g + 1];
    float s0 = 0.f, s1 = 0.f;
    for (int r = r0 + wv; r < r1; r += 4) {
        unsigned u = h[(size_t)r * 64 + lane];
        float v0 = __uint_as_float(u << 16);
        float v1 = __uint_as_float(u & 0xFFFF0000u);
        s0 += fmaxf(fmaf(v0, sc0, sh0), 0.f);
        s1 += fmaxf(fmaf(v1, sc1, sh1), 0.f);
    }
    __shared__ float sP[4][128];
    sP[wv][c0] = s0;
    sP[wv][c0 + 1] = s1;
    __syncthreads();

    __shared__ float zs[160];
    __shared__ float red[4];
    float invc = 1.f / fmaxf((float)(r1 - r0), 1.f);
    if (t < 128)
        zs[t] = (sP[0][t] + sP[1][t] + sP[2][t] + sP[3][t]) * invc;
    else if (t < 160)
        zs[t] = gf[(size_t)g * 32 + (t - 128)];
    __syncthreads();

    float acc = b1[t];
#pragma unroll 8
    for (int i = 0; i < 160; i++) acc = fmaf(zs[i], W1[i * 256 + t], acc);
    acc = fmaxf(acc, 0.f);
    float part = acc * W2[t];
    part += __shfl_xor(part, 32, 64);
    part += __shfl_xor(part, 16, 64);
    part += __shfl_xor(part, 8, 64);
    part += __shfl_xor(part, 4, 64);
    part += __shfl_xor(part, 2, 64);
    part += __shfl_xor(part, 1, 64);
    if ((t & 63) == 0) red[t >> 6] = part;
    __syncthreads();
    if (t == 0) out[g] = red[0] + red[1] + red[2] + red[3] + b2[0];
}

extern "C" void kernel_launch(void* const* d_in, const int* in_sizes, int n_in,
                              void* d_out, int out_size, void* d_ws, size_t ws_size,
                              hipStream_t stream) {
    (void)in_sizes; (void)n_in; (void)out_size; (void)ws_size;

    const float* x     = (const float*)d_in[0];
    const int*   ei    = (const int*)d_in[1];
    const int*   batch = (const int*)d_in[2];
    const float* gf    = (const float*)d_in[3];
    const float* Wl1 = (const float*)d_in[4];
    const float* bl1 = (const float*)d_in[5];
    const float* Wr1 = (const float*)d_in[6];
    const float* br1 = (const float*)d_in[7];
    const float* att1  = (const float*)d_in[8];
    const float* bias1 = (const float*)d_in[9];
    const float* g1  = (const float*)d_in[10];
    const float* be1 = (const float*)d_in[11];
    const float* Wl2 = (const float*)d_in[12];
    const float* bl2 = (const float*)d_in[13];
    const float* Wr2 = (const float*)d_in[14];
    const float* br2 = (const float*)d_in[15];
    const float* att2  = (const float*)d_in[16];
    const float* bias2 = (const float*)d_in[17];
    const float* g2  = (const float*)d_in[18];
    const float* be2 = (const float*)d_in[19];
    const float* Wfc1 = (const float*)d_in[20];
    const float* bfc1 = (const float*)d_in[21];
    const float* Wfc2 = (const float*)d_in[22];
    const float* bfc2 = (const float*)d_in[23];
    float* out = (float*)d_out;

    char* ws = (char*)d_ws;
    unsigned short* xl = (unsigned short*)(ws + 0);            // 25.6 MB bf16
    unsigned short* xr = (unsigned short*)(ws + 25600000);     // 25.6 MB bf16
    unsigned* h     = (unsigned*)(ws + 51200000);              // 25.6 MB bf16 packed
    int*   colA     = (int*)(ws + 76800000);                   // 9.63 MB (bucketed)
    int*   bktBuf   = (int*)(ws + 86434560);                   // 9.63 MB packed ints
    int*   bucketCur= (int*)(ws + 96068608);                   // 1 KB
    float* SP       = (float*)(ws + 96069632);                 // 64 KB (64 slots)
    int*   cntA     = (int*)(ws + 96135168);                   // 400 KB
    int*   startA   = (int*)(ws + 96535168);                   // 400 KB
    float* scsh     = (float*)(ws + 96935168);                 // 2 KB: sc1|sh1
    int*   gstart   = (int*)(ws + 96937216);                   // 4.1 KB
    unsigned short* Wimg1 = (unsigned short*)(ws + 96941568);  // 64 KB
    unsigned short* Wimg2 = (unsigned short*)(ws + 97007104);  // 64 KB
    float* Al       = (float*)(ws + 97072640);                 // 1.6 MB [N][4]

    // prep (W images, graph bounds, zero bucketCur/SP) + CSR build
    k_prep<<<425, 256, 0, stream>>>(Wl1, Wr1, Wl2, Wr2, Wimg1, Wimg2,
                                    batch, gstart, bucketCur, SP);
    k_part<<<(EP + 4095) / 4096, 256, 0, stream>>>(ei, bucketCur, bktBuf);
    k_build<<<NB, 512, 0, stream>>>(bktBuf, bucketCur, startA, cntA, colA);

    int gemm_grid = (N_NODES + 63) / 64;

    // Layer 1
    k_gemm<false, false><<<gemm_grid, 256, 0, stream>>>(x, Wimg1, bl1, br1,
                                                        nullptr, nullptr, att1, Al,
                                                        xl, xr, N_NODES);
    k_agg<<<N_NODES / 4, 256, 0, stream>>>((const unsigned*)xl, (const unsigned*)xr,
                                           startA, cntA, (const unsigned*)colA,
                                           att1, bias1, Al, h, SP);
    k_bnfinal<<<1, 128, 0, stream>>>(SP, g1, be1, scsh + 0, scsh + 128);

    // Layer 2 (BN1 apply + ReLU fused into GEMM A-staging, bf16 input)
    k_gemm<true, true><<<gemm_grid, 256, 0, stream>>>(h, Wimg2, bl2, br2,
                                                      scsh + 0, scsh + 128, att2, Al,
                                                      xl, xr, N_NODES);
    k_agg<<<N_NODES / 4, 256, 0, stream>>>((const unsigned*)xl, (const unsigned*)xr,
                                           startA, cntA, (const unsigned*)colA,
                                           att2, bias2, Al, h, SP);

    // Tail: BN2 finalize (inline) + pool + MLP, one launch
    k_tail<<<NG, 256, 0, stream>>>(h, gstart, gf, SP, g2, be2,
                                   Wfc1, bfc1, Wfc2, bfc2, out);
}

// Round 17
// 296.183 us; speedup vs baseline: 6.1860x; 1.0103x over previous
//
#include <hip/hip_runtime.h>
#include <hip/hip_bf16.h>

#define N_NODES 100000
#define E_EDGES 1600000
#define EP (E_EDGES + N_NODES)
#define NG 1024
#define NEG 0.2f
#define EPS_BN 1e-5f
#define LOG2E 1.44269504088896f

#define NB 196        // dst buckets of 512 nodes
#define BCAP 12288    // per-bucket capacity (mean 8704)
#define NSLOT 64      // BN partial slots (low same-address contention)

typedef __attribute__((ext_vector_type(8))) short bf8_t;
typedef __attribute__((ext_vector_type(4))) float f4_t;

// pack 2 f32 -> 2 bf16 (RNE) in one u32; compiles to v_cvt_pk_bf16_f32.
__device__ __forceinline__ unsigned pk2(float lo, float hi) {
    __hip_bfloat162 b = __float22bfloat162_rn(make_float2(lo, hi));
    union { __hip_bfloat162 b; unsigned u; } c;
    c.b = b;
    return c.u;
}

// 16-lane sum via mov_dpp row_ror butterfly; result broadcast to 16 lanes.
__device__ __forceinline__ float rsum16(float p) {
    p += __int_as_float(__builtin_amdgcn_mov_dpp(__float_as_int(p), 0x128, 0xf, 0xf, true));
    p += __int_as_float(__builtin_amdgcn_mov_dpp(__float_as_int(p), 0x124, 0xf, 0xf, true));
    p += __int_as_float(__builtin_amdgcn_mov_dpp(__float_as_int(p), 0x122, 0xf, 0xf, true));
    p += __int_as_float(__builtin_amdgcn_mov_dpp(__float_as_int(p), 0x121, 0xf, 0xf, true));
    return p;
}

// 4-lane (quad) sum via quad_perm DPP; result broadcast to all 4 lanes.
__device__ __forceinline__ float quadsum(float p) {
    p += __int_as_float(__builtin_amdgcn_mov_dpp(__float_as_int(p), 0xB1, 0xf, 0xf, true)); // [1,0,3,2]
    p += __int_as_float(__builtin_amdgcn_mov_dpp(__float_as_int(p), 0x4E, 0xf, 0xf, true)); // [2,3,0,1]
    return p;
}

__device__ __forceinline__ void unpack8(const int4& d, float* z) {
    unsigned a = (unsigned)d.x, b = (unsigned)d.y, c = (unsigned)d.z, w = (unsigned)d.w;
    z[0] = __uint_as_float(a << 16); z[1] = __uint_as_float(a & 0xFFFF0000u);
    z[2] = __uint_as_float(b << 16); z[3] = __uint_as_float(b & 0xFFFF0000u);
    z[4] = __uint_as_float(c << 16); z[5] = __uint_as_float(c & 0xFFFF0000u);
    z[6] = __uint_as_float(w << 16); z[7] = __uint_as_float(w & 0xFFFF0000u);
}

// ================= CSR build: partition -> per-bucket build (packed int) =====
// buf entry = (src << 9) | (dst & 511); bucket = dst >> 9.
__global__ __launch_bounds__(256) void k_part(const int* __restrict__ ei,
                                              int* __restrict__ bucketCur,
                                              int* __restrict__ buf) {
    __shared__ int lh[NB], lb[NB];
    int t = threadIdx.x;
    for (int i = t; i < NB; i += 256) lh[i] = 0;
    __syncthreads();
    int base = blockIdx.x * 4096;
    int pk[16];
    int bk[16];
    int rk[16];
#pragma unroll
    for (int i = 0; i < 16; i++) {
        int idx = base + i * 256 + t;
        int s, d;
        if (idx < E_EDGES) { s = ei[idx]; d = ei[E_EDGES + idx]; }
        else if (idx < EP) { s = d = idx - E_EDGES; }
        else { s = 0; d = -1; }
        pk[i] = (s << 9) | (d & 511);
        bk[i] = d >> 9;
        rk[i] = (d >= 0) ? atomicAdd(&lh[d >> 9], 1) : 0;
    }
    __syncthreads();
    for (int i = t; i < NB; i += 256) lb[i] = atomicAdd(&bucketCur[i], lh[i]);
    __syncthreads();
#pragma unroll
    for (int i = 0; i < 16; i++) {
        int bkt = bk[i];
        if (bkt >= 0)
            buf[(size_t)bkt * BCAP + lb[bkt] + rk[i]] = pk[i];
    }
}

// per-bucket: histogram -> LDS scan -> startA/cntA -> place colA (byte offsets)
// + zero a 16-int tail pad after each bucket's used region (pipeline over-reads)
__global__ __launch_bounds__(512) void k_build(const int* __restrict__ buf,
                                               const int* __restrict__ bcnt,
                                               int* __restrict__ startA,
                                               int* __restrict__ cntA,
                                               int* __restrict__ colA) {
    __shared__ int h[512];
    __shared__ int s[512];
    int b = blockIdx.x, t = threadIdx.x;
    h[t] = 0;
    __syncthreads();
    int n = bcnt[b];
    const int* p = buf + (size_t)b * BCAP;
    for (int i = t; i < n; i += 512) atomicAdd(&h[p[i] & 511], 1);
    __syncthreads();
    int v = h[t];
    s[t] = v;
    __syncthreads();
    for (int o = 1; o < 512; o <<= 1) {
        int u = (t >= o) ? s[t - o] : 0;
        __syncthreads();
        s[t] += u;
        __syncthreads();
    }
    int myStart = b * BCAP + s[t] - v;   // exclusive prefix within bucket
    int node = (b << 9) + t;
    if (node < N_NODES) {
        startA[node] = myStart;
        cntA[node] = v;
    }
    h[t] = myStart;                      // reuse as running cursor
    __syncthreads();
    for (int i = t; i < n; i += 512) {
        int e = p[i];
        int r = atomicAdd(&h[e & 511], 1);
        colA[r] = (e >> 9) << 8;         // src * 256 (byte offset into xl)
    }
    if (t < 16) colA[b * BCAP + n + t] = 0;   // tail pad (stray reads -> node 0)
}

// === prep: wconv L1+L2 (0..31) + gstart (32..422) + zero (423..425) ==========
__global__ __launch_bounds__(256) void k_prep(
    const float* __restrict__ Wl1, const float* __restrict__ Wr1,
    const float* __restrict__ Wl2, const float* __restrict__ Wr2,
    unsigned short* __restrict__ img1, unsigned short* __restrict__ img2,
    const int* __restrict__ batch, int* __restrict__ gstart,
    int* __restrict__ bucketCur, float* __restrict__ SP) {
    int blk = blockIdx.x;
    int t = threadIdx.x;
    if (blk < 32) {
        int lay = blk >> 4;
        int g = (blk & 15) * 256 + t;   // 4096 chunks per layer
        int m = g >> 11, n = (g >> 4) & 127, kb = g & 15;
        const float* W = lay ? (m ? Wr2 : Wl2) : (m ? Wr1 : Wl1);
        unsigned short* img = lay ? img2 : img1;
        unsigned vw[4];
#pragma unroll
        for (int j = 0; j < 4; j++)
            vw[j] = pk2(W[(kb * 8 + 2 * j) * 128 + n],
                        W[(kb * 8 + 2 * j + 1) * 128 + n]);
        int off = m * 32768 + n * 256 + kb * 16;
        *(int4*)((char*)img + off) = *(int4*)vw;
    } else if (blk < 423) {
        int i = (blk - 32) * 256 + t;
        if (i >= N_NODES) return;
        int b = batch[i];
        int prev = (i == 0) ? -1 : batch[i - 1];
        for (int g = prev + 1; g <= b; g++) gstart[g] = i;
        if (i == N_NODES - 1)
            for (int g = b + 1; g <= NG; g++) gstart[g] = N_NODES;
    } else if (blk == 423) {
        if (t < NB) bucketCur[t] = 0;
    } else {
        // blocks 424/425: zero SP1 / SP2 (each NSLOT*256 floats = 64 KB)
        float* base = SP + (size_t)(blk - 424) * (NSLOT * 256);
        float4 zz = {0.f, 0.f, 0.f, 0.f};
#pragma unroll
        for (int j = 0; j < 16; ++j)
            *(float4*)&base[(j * 256 + t) * 4] = zz;
    }
}

// ================= MFMA dual GEMM: xl = A@Wl + bl, xr = A@Wr + br (bf16) =====
// W fragments straight from global (L2-hot). When AFF: per-block inline BN
// finalize from SP partials (L2-hot redundant reduce — k_tail-proven pattern),
// then BN-affine+relu fused into A staging. Fused epilogue also emits
// Al[n][h] = 0.6*log2e * att_h . xl[n]  (from f32 accumulators, mat=0 waves).
template<bool AFF, bool BF16IN>
__global__ __launch_bounds__(256) void k_gemm(
    const void* __restrict__ Ain, const unsigned short* __restrict__ Wimg,
    const float* __restrict__ bl, const float* __restrict__ br,
    const float* __restrict__ SPin, const float* __restrict__ bng,
    const float* __restrict__ bnbe,
    const float* __restrict__ att, float* __restrict__ Al,
    unsigned short* __restrict__ xl, unsigned short* __restrict__ xr, int M)
{
    __shared__ char lds[32768];
    short* As = (short*)lds;                    // 16384 B (staged A)
    float* fin = (float*)(lds + 16384);         // 256 f32 (BN reduce scratch)
    float* sSC = (float*)(lds + 17408);         // 128 f32
    float* sSH = (float*)(lds + 17920);         // 128 f32

    int t = threadIdx.x;
    int lane = t & 63;
    int w = t >> 6;
    int brow = blockIdx.x * 64;

    int rl = lane & 15;
    int kh = lane >> 4;
    int mat = w >> 1;
    int c0 = (w & 1) * 64;

    // ---- inline BN finalize (AFF only): SP partials -> sSC/sSH in LDS ----
    if (AFF) {
        int c = t & 127, half = t >> 7;
        float v = 0.f;
#pragma unroll
        for (int j = 0; j < NSLOT; ++j) v += SPin[j * 256 + half * 128 + c];
        fin[t] = v;
        __syncthreads();
        if (t < 128) {
            float s = fin[t], q = fin[128 + t];
            float mu = s * (1.f / N_NODES);
            float var = q * (1.f / N_NODES) - mu * mu;
            float sv = rsqrtf(var + EPS_BN) * bng[t];
            sSC[t] = sv;
            sSH[t] = bnbe[t] - mu * sv;
        }
        __syncthreads();
    }

    // ---- B fragments from global (issued before A staging) ----
    const char* wbase = (const char*)Wimg + mat * 32768;
    bf8_t bfr[4][4];
#pragma unroll
    for (int s = 0; s < 4; ++s)
#pragma unroll
        for (int j = 0; j < 4; ++j)
            bfr[s][j] = *(const bf8_t*)(wbase + (c0 + 16 * j + rl) * 256 + s * 64 + kh * 16);

    // ---- stage A (f32 or packed-bf16 input; optional BN-affine+relu) ----
    {
        int kbase = (t & 7) * 16;
        float scv[16], shv[16];
        if (AFF) {
#pragma unroll
            for (int q = 0; q < 4; ++q) {
                float4 a4 = *(const float4*)&sSC[kbase + q * 4];
                float4 b4 = *(const float4*)&sSH[kbase + q * 4];
                scv[q*4+0]=a4.x; scv[q*4+1]=a4.y; scv[q*4+2]=a4.z; scv[q*4+3]=a4.w;
                shv[q*4+0]=b4.x; shv[q*4+1]=b4.y; shv[q*4+2]=b4.z; shv[q*4+3]=b4.w;
            }
        }
#pragma unroll
        for (int p = 0; p < 2; ++p) {
            int row = p * 32 + (t >> 3);
            int ar = brow + row; if (ar >= M) ar = M - 1;
            unsigned vb32[8];
            if (BF16IN) {
                const unsigned* src = (const unsigned*)Ain + (size_t)ar * 64 + (kbase >> 1);
                int4 r0 = *(const int4*)src;
                int4 r1 = *(const int4*)(src + 4);
                unsigned ua[8] = {(unsigned)r0.x,(unsigned)r0.y,(unsigned)r0.z,(unsigned)r0.w,
                                  (unsigned)r1.x,(unsigned)r1.y,(unsigned)r1.z,(unsigned)r1.w};
#pragma unroll
                for (int m = 0; m < 8; ++m) {
                    float f0 = __uint_as_float(ua[m] << 16);
                    float f1 = __uint_as_float(ua[m] & 0xFFFF0000u);
                    if (AFF) {
                        f0 = fmaxf(fmaf(f0, scv[2*m], shv[2*m]), 0.f);
                        f1 = fmaxf(fmaf(f1, scv[2*m+1], shv[2*m+1]), 0.f);
                        vb32[m] = pk2(f0, f1);
                    } else {
                        vb32[m] = ua[m];   // passthrough, already bf16 pair
                    }
                }
            } else {
                const float* src = (const float*)Ain + (size_t)ar * 128 + kbase;
#pragma unroll
                for (int q = 0; q < 4; ++q) {
                    float4 x4 = *(const float4*)&src[q * 4];
                    float vv[4] = {x4.x, x4.y, x4.z, x4.w};
                    if (AFF) {
#pragma unroll
                        for (int e = 0; e < 4; ++e)
                            vv[e] = fmaxf(fmaf(vv[e], scv[q*4+e], shv[q*4+e]), 0.f);
                    }
                    vb32[q * 2]     = pk2(vv[0], vv[1]);
                    vb32[q * 2 + 1] = pk2(vv[2], vv[3]);
                }
            }
            int swz = (row & 7) << 4;
#pragma unroll
            for (int u = 0; u < 2; ++u) {
                int off = (row * 256 + kbase * 2 + u * 16) ^ swz;
                *(int4*)((char*)As + off) = *(int4*)&vb32[u * 4];
            }
        }
    }
    __syncthreads();

    // ---- compute ----
    int swz = (rl & 7) << 4;
    f4_t acc[4][4];
#pragma unroll
    for (int i = 0; i < 4; ++i)
#pragma unroll
        for (int j = 0; j < 4; ++j) { f4_t z = {0.f,0.f,0.f,0.f}; acc[i][j] = z; }

    const char* Asc = (const char*)As;
#pragma unroll
    for (int s = 0; s < 4; ++s) {
        int kb2 = (s * 32 + kh * 8) * 2;
        bf8_t af[4];
#pragma unroll
        for (int i = 0; i < 4; ++i) {
            int row = 16 * i + rl;
            af[i] = *(const bf8_t*)(Asc + ((row * 256 + kb2) ^ swz));
        }
#pragma unroll
        for (int i = 0; i < 4; ++i)
#pragma unroll
            for (int j = 0; j < 4; ++j)
                acc[i][j] = __builtin_amdgcn_mfma_f32_16x16x32_bf16(af[i], bfr[s][j], acc[i][j], 0, 0, 0);
    }

    // ---- epilogue ----
    __syncthreads();
    short* Cs = (short*)lds;   // [64][256] bf16, swizzled (32 KB, reuses all)
    const float* bb = mat ? br : bl;
    float blv[4];
#pragma unroll
    for (int j = 0; j < 4; ++j) blv[j] = bb[c0 + 16 * j + rl];

    // fused Al (source-logit) for xl waves: per-head 32-ch dot via rsum16.
    if (mat == 0) {
        const float sAl = 0.6f * LOG2E;
        float ap0 = att[c0 + rl] * sAl;
        float ap1 = att[c0 + 16 + rl] * sAl;
        float ap2 = att[c0 + 32 + rl] * sAl;
        float ap3 = att[c0 + 48 + rl] * sAl;
        float cl = fmaf(ap0, blv[0], ap1 * blv[1]);
        float ch = fmaf(ap2, blv[2], ap3 * blv[3]);
        int hbase = c0 >> 5;   // 0 (w=0) or 2 (w=1)
#pragma unroll
        for (int i = 0; i < 4; ++i)
#pragma unroll
            for (int q = 0; q < 4; ++q) {
                float pl = fmaf(ap0, acc[i][0][q], fmaf(ap1, acc[i][1][q], cl));
                float ph = fmaf(ap2, acc[i][2][q], fmaf(ap3, acc[i][3][q], ch));
                pl = rsum16(pl);
                ph = rsum16(ph);
                int node = brow + 16 * i + kh * 4 + q;
                if (rl == 0 && node < M) {
                    float2 w2 = make_float2(pl, ph);
                    *(float2*)&Al[(size_t)node * 4 + hbase] = w2;
                }
            }
    }

#pragma unroll
    for (int i = 0; i < 4; ++i)
#pragma unroll
        for (int j = 0; j < 4; ++j) {
            int col = mat * 128 + c0 + 16 * j + rl;
            unsigned u01 = pk2(acc[i][j][0] + blv[j], acc[i][j][1] + blv[j]);
            unsigned u23 = pk2(acc[i][j][2] + blv[j], acc[i][j][3] + blv[j]);
            unsigned short vq[4] = {(unsigned short)u01, (unsigned short)(u01 >> 16),
                                    (unsigned short)u23, (unsigned short)(u23 >> 16)};
#pragma unroll
            for (int q = 0; q < 4; ++q) {
                int row = 16 * i + kh * 4 + q;
                int off = (row * 512 + col * 2) ^ ((row & 7) << 4);
                *(unsigned short*)((char*)Cs + off) = vq[q];
            }
        }
    __syncthreads();
#pragma unroll
    for (int rep = 0; rep < 8; ++rep) {
        int unit = rep * 256 + t;
        int row = unit >> 5;
        int slot = unit & 31;
        int gr = brow + row;
        if (gr < M) {
            int off = (row * 512 + slot * 16) ^ ((row & 7) << 4);
            int4 vv = *(const int4*)((char*)Cs + off);
            unsigned short* O = (slot < 16) ? xl : xr;
            int gcol = (slot & 15) * 8;
            *(int4*)&O[(size_t)gr * 128 + gcol] = vv;
        }
    }
}

// ===== fused edge softmax + aggregation + BN stats (fire-and-exit epilogue) ==
__global__ __launch_bounds__(256) void k_agg(
    const unsigned* __restrict__ xl, const unsigned* __restrict__ xr,
    const int* __restrict__ startA, const int* __restrict__ cntA,
    const unsigned* __restrict__ colB,
    const float* __restrict__ att, const float* __restrict__ bias,
    const float* __restrict__ Al, unsigned* __restrict__ hout,
    float* __restrict__ SP)
{
    int tid = threadIdx.x;
    int lane = tid & 63;
    int wv = tid >> 6;
    int n = blockIdx.x * 4 + wv;
    int e = lane >> 4;                 // edge slot 0..3
    int hq = lane & 15;                // h*4+q
    int h4 = (hq >> 2) * 4;            // byte offset of head in Al row
    unsigned hq16 = (unsigned)hq * 16u;
    const char* xlb = (const char*)xl;
    const char* alb = (const char*)Al;

    // att' slice (8 ch of this head-quarter), pre-scaled by 0.4*log2e
    float ap[8];
    {
        float4 q0 = *(const float4*)&att[hq * 8];
        float4 q1 = *(const float4*)&att[hq * 8 + 4];
        const float s = 0.4f * LOG2E;
        ap[0]=q0.x*s; ap[1]=q0.y*s; ap[2]=q0.z*s; ap[3]=q0.w*s;
        ap[4]=q1.x*s; ap[5]=q1.y*s; ap[6]=q1.z*s; ap[7]=q1.w*s;
    }
    // xr slice for this node
    float zx[8];
    {
        int4 xru = *(const int4*)((const char*)xr + (size_t)n * 256 + hq16);
        unpack8(xru, zx);
    }
    // Snode = 0.6*log2e * att_h . xr[n]  (= 1.5 * quadsum(dot(ap, zx)))
    float arp = ap[0] * zx[0];
#pragma unroll
    for (int c = 1; c < 8; ++c) arp = fmaf(ap[c], zx[c], arp);
    float Snode = 1.5f * quadsum(arp);

    int a0i = startA[n];
    int cn = cntA[n];                  // >= 1 (self loop)
    int nb = (cn + 3) >> 2;

    // pipeline prologue (bucket tail pads zeroed -> stray reads hit node 0,
    // masked out by wg)
    unsigned off0 = colB[a0i + e];
    float al0 = *(const float*)(alb + ((off0 >> 4) & ~15u) + h4);
    int4 d0 = *(const int4*)(xlb + off0 + hq16);
    unsigned off1 = off0;
    if (nb > 1) off1 = colB[a0i + 4 + e];

    float acc[8] = {0.f,0.f,0.f,0.f,0.f,0.f,0.f,0.f};
    float wsum = 0.f;

    for (int b = 0; b < nb; ++b) {
        unsigned off2 = off1;
        if (b + 2 < nb) off2 = colB[a0i + (b + 2) * 4 + e];
        float al1 = al0; int4 d1 = d0;
        if (b + 1 < nb) {
            al1 = *(const float*)(alb + ((off1 >> 4) & ~15u) + h4);
            d1 = *(const int4*)(xlb + off1 + hq16);
        }
        float z[8]; unpack8(d0, z);
        float t0 = z[0] + zx[0];
        float D = ap[0] * fabsf(t0);
#pragma unroll
        for (int c = 1; c < 8; ++c) {
            float tc = z[c] + zx[c];
            D = fmaf(ap[c], fabsf(tc), D);
        }
        D = quadsum(D);
        float wg = exp2f(al0 + Snode + D);
        if (b == nb - 1) wg = (b * 4 + e < cn) ? wg : 0.f;   // tail mask
#pragma unroll
        for (int c = 0; c < 8; ++c) acc[c] = fmaf(wg, z[c], acc[c]);
        wsum += wg;
        off0 = off1; off1 = off2; al0 = al1; d0 = d1;
    }

    // reduce across the 4 edge groups (lanes xor 16, 32)
#pragma unroll
    for (int c = 0; c < 8; ++c) {
        acc[c] += __shfl_xor(acc[c], 16, 64);
        acc[c] += __shfl_xor(acc[c], 32, 64);
    }
    wsum += __shfl_xor(wsum, 16, 64);
    wsum += __shfl_xor(wsum, 32, 64);

    float inv = 1.f / wsum;
    float4 b0 = *(const float4*)&bias[hq * 8];
    float4 b1 = *(const float4*)&bias[hq * 8 + 4];
    float bv[8] = {b0.x,b0.y,b0.z,b0.w,b1.x,b1.y,b1.z,b1.w};
    float ov[8];
    unsigned r[4];
#pragma unroll
    for (int k = 0; k < 4; ++k) {
        float o0 = fmaf(acc[2*k],     inv, bv[2*k]);
        float o1 = fmaf(acc[2*k + 1], inv, bv[2*k + 1]);
        ov[2*k] = o0; ov[2*k+1] = o1;
        r[k] = pk2(o0, o1);
    }

    // BN stats: per-node (lane<16 holds the 128 channels, 8 each)
    __shared__ float sO[4][128], sQ[4][128];
    if (lane < 16) {
        *(int4*)((char*)hout + (size_t)n * 256 + hq16) = *(int4*)r;
#pragma unroll
        for (int c = 0; c < 8; ++c) {
            sO[wv][hq * 8 + c] = ov[c];
            sQ[wv][hq * 8 + c] = ov[c] * ov[c];
        }
    }
    __syncthreads();
    if (tid < 128) {
        float s = sO[0][tid] + sO[1][tid] + sO[2][tid] + sO[3][tid];
        float q = sQ[0][tid] + sQ[1][tid] + sQ[2][tid] + sQ[3][tid];
        float* slot = SP + (size_t)(blockIdx.x & (NSLOT - 1)) * 256;
        atomicAdd(&slot[tid], s);
        atomicAdd(&slot[128 + tid], q);
    }
    // fire-and-exit: no trailing barrier, no completion handshake.
}

// ====== tail: BN2 finalize (inline, per block) + mean pool + MLP head =======
__global__ __launch_bounds__(256) void k_tail(
    const unsigned* __restrict__ h, const int* __restrict__ gstart,
    const float* __restrict__ gf, const float* __restrict__ SP,
    const float* __restrict__ gg, const float* __restrict__ be,
    const float* __restrict__ W1, const float* __restrict__ b1,
    const float* __restrict__ W2, const float* __restrict__ b2,
    float* __restrict__ out)
{
    int g = blockIdx.x;
    int t = threadIdx.x;
    int wv = t >> 6;
    int lane = t & 63;
    int c0 = lane * 2;

    // BN2 finalize, redundant per block (SP is L2-hot)
    __shared__ float sSC[128], sSH[128], fin[256];
    {
        int c = t & 127, half = t >> 7;
        float v = 0.f;
#pragma unroll
        for (int j = 0; j < NSLOT; ++j) v += SP[j * 256 + half * 128 + c];
        fin[t] = v;
    }
    __syncthreads();
    if (t < 128) {
        float s = fin[t], q = fin[128 + t];
        float mu = s * (1.f / N_NODES);
        float var = q * (1.f / N_NODES) - mu * mu;
        float sv = rsqrtf(var + EPS_BN) * gg[t];
        sSC[t] = sv;
        sSH[t] = be[t] - mu * sv;
    }
    __syncthreads();

    float sc0 = sSC[c0], sc1 = sSC[c0 + 1], sh0 = sSH[c0], sh1 = sSH[c0 + 1];
    int r0 = gstart[g], r1 = gstart[g + 1];
    float s0 = 0.f, s1 = 0.f;
    for (int r = r0 + wv; r < r1; r += 4) {
        unsigned u = h[(size_t)r * 64 + lane];
        float v0 = __uint_as_float(u << 16);
        float v1 = __uint_as_float(u & 0xFFFF0000u);
        s0 += fmaxf(fmaf(v0, sc0, sh0), 0.f);
        s1 += fmaxf(fmaf(v1, sc1, sh1), 0.f);
    }
    __shared__ float sP[4][128];
    sP[wv][c0] = s0;
    sP[wv][c0 + 1] = s1;
    __syncthreads();

    __shared__ float zs[160];
    __shared__ float red[4];
    float invc = 1.f / fmaxf((float)(r1 - r0), 1.f);
    if (t < 128)
        zs[t] = (sP[0][t] + sP[1][t] + sP[2][t] + sP[3][t]) * invc;
    else if (t < 160)
        zs[t] = gf[(size_t)g * 32 + (t - 128)];
    __syncthreads();

    float acc = b1[t];
#pragma unroll 8
    for (int i = 0; i < 160; i++) acc = fmaf(zs[i], W1[i * 256 + t], acc);
    acc = fmaxf(acc, 0.f);
    float part = acc * W2[t];
    part += __shfl_xor(part, 32, 64);
    part += __shfl_xor(part, 16, 64);
    part += __shfl_xor(part, 8, 64);
    part += __shfl_xor(part, 4, 64);
    part += __shfl_xor(part, 2, 64);
    part += __shfl_xor(part, 1, 64);
    if ((t & 63) == 0) red[t >> 6] = part;
    __syncthreads();
    if (t == 0) out[g] = red[0] + red[1] + red[2] + red[3] + b2[0];
}

extern "C" void kernel_launch(void* const* d_in, const int* in_sizes, int n_in,
                              void* d_out, int out_size, void* d_ws, size_t ws_size,
                              hipStream_t stream) {
    (void)in_sizes; (void)n_in; (void)out_size; (void)ws_size;

    const float* x     = (const float*)d_in[0];
    const int*   ei    = (const int*)d_in[1];
    const int*   batch = (const int*)d_in[2];
    const float* gf    = (const float*)d_in[3];
    const float* Wl1 = (const float*)d_in[4];
    const float* bl1 = (const float*)d_in[5];
    const float* Wr1 = (const float*)d_in[6];
    const float* br1 = (const float*)d_in[7];
    const float* att1  = (const float*)d_in[8];
    const float* bias1 = (const float*)d_in[9];
    const float* g1  = (const float*)d_in[10];
    const float* be1 = (const float*)d_in[11];
    const float* Wl2 = (const float*)d_in[12];
    const float* bl2 = (const float*)d_in[13];
    const float* Wr2 = (const float*)d_in[14];
    const float* br2 = (const float*)d_in[15];
    const float* att2  = (const float*)d_in[16];
    const float* bias2 = (const float*)d_in[17];
    const float* g2  = (const float*)d_in[18];
    const float* be2 = (const float*)d_in[19];
    const float* Wfc1 = (const float*)d_in[20];
    const float* bfc1 = (const float*)d_in[21];
    const float* Wfc2 = (const float*)d_in[22];
    const float* bfc2 = (const float*)d_in[23];
    float* out = (float*)d_out;

    char* ws = (char*)d_ws;
    unsigned short* xl = (unsigned short*)(ws + 0);            // 25.6 MB bf16
    unsigned short* xr = (unsigned short*)(ws + 25600000);     // 25.6 MB bf16
    unsigned* h     = (unsigned*)(ws + 51200000);              // 25.6 MB bf16 packed
    int*   colA     = (int*)(ws + 76800000);                   // 9.63 MB (bucketed)
    int*   bktBuf   = (int*)(ws + 86434560);                   // 9.63 MB packed ints
    int*   bucketCur= (int*)(ws + 96068608);                   // 1 KB
    float* SP       = (float*)(ws + 96069632);                 // 128 KB (SP1|SP2)
    int*   cntA     = (int*)(ws + 96200704);                   // 400 KB
    int*   startA   = (int*)(ws + 96600704);                   // 400 KB
    int*   gstart   = (int*)(ws + 97000704);                   // 4.1 KB
    unsigned short* Wimg1 = (unsigned short*)(ws + 97004928);  // 64 KB
    unsigned short* Wimg2 = (unsigned short*)(ws + 97070464);  // 64 KB
    float* Al       = (float*)(ws + 97136000);                 // 1.6 MB [N][4]

    float* SP1 = SP;
    float* SP2 = SP + NSLOT * 256;

    // prep (W images, graph bounds, zero bucketCur/SP1/SP2) + CSR build
    k_prep<<<426, 256, 0, stream>>>(Wl1, Wr1, Wl2, Wr2, Wimg1, Wimg2,
                                    batch, gstart, bucketCur, SP);
    k_part<<<(EP + 4095) / 4096, 256, 0, stream>>>(ei, bucketCur, bktBuf);
    k_build<<<NB, 512, 0, stream>>>(bktBuf, bucketCur, startA, cntA, colA);

    int gemm_grid = (N_NODES + 63) / 64;

    // Layer 1
    k_gemm<false, false><<<gemm_grid, 256, 0, stream>>>(x, Wimg1, bl1, br1,
                                                        nullptr, nullptr, nullptr,
                                                        att1, Al, xl, xr, N_NODES);
    k_agg<<<N_NODES / 4, 256, 0, stream>>>((const unsigned*)xl, (const unsigned*)xr,
                                           startA, cntA, (const unsigned*)colA,
                                           att1, bias1, Al, h, SP1);

    // Layer 2 (BN1 finalize inline from SP1 + affine+ReLU fused into A-staging)
    k_gemm<true, true><<<gemm_grid, 256, 0, stream>>>(h, Wimg2, bl2, br2,
                                                      SP1, g1, be1,
                                                      att2, Al, xl, xr, N_NODES);
    k_agg<<<N_NODES / 4, 256, 0, stream>>>((const unsigned*)xl, (const unsigned*)xr,
                                           startA, cntA, (const unsigned*)colA,
                                           att2, bias2, Al, h, SP2);

    // Tail: BN2 finalize (inline from SP2) + pool + MLP, one launch
    k_tail<<<NG, 256, 0, stream>>>(h, gstart, gf, SP2, g2, be2,
                                   Wfc1, bfc1, Wfc2, bfc2, out);
}